// Round 10
// baseline (144.986 us; speedup 1.0000x reference)
//
#include <hip/hip_runtime.h>
#include <hip/hip_bf16.h>
#include <math.h>

#define M_TOK 16
#define NDIM  2048
#define DHEAD 128
#define NHEAD 16
#define MAXLEN 8448
#define FFN   8192
#define TC    128
#define NCH   65   // 64 cache chunks of 128 + 1 chunk of the 16 new rows
#define LN_EPS 1e-5f
#define RSQRT_D 0.08838834764831845f  // 1/sqrt(128)

#define AS1 __attribute__((address_space(1)))
#define AS3 __attribute__((address_space(3)))

// async global->LDS DMA: lane i writes 16B at lds_base + i*16 (wave-uniform base)
__device__ __forceinline__ void gload_lds16(const float* g, float* l) {
    __builtin_amdgcn_global_load_lds((AS1 void*)g, (AS3 void*)l, 16, 0, 0);
}

// ================= fold reduce =================
template<int H>
__device__ __forceinline__ void fold_step(float* v, int lane, int o) {
    bool hi = (lane & o) != 0;
    #pragma unroll
    for (int i = 0; i < H; ++i) {
        float send = hi ? v[i] : v[i + H];
        float keep = hi ? v[i + H] : v[i];
        v[i] = keep + __shfl_xor(send, o);
    }
}

// 32 partials per lane -> lane L holds the all-lane sum of v[(L>>1)&31]
__device__ __forceinline__ void fold32(float* v, int lane) {
    fold_step<16>(v, lane, 32);
    fold_step<8>(v, lane, 16);
    fold_step<4>(v, lane, 8);
    fold_step<2>(v, lane, 4);
    fold_step<1>(v, lane, 2);
    v[0] += __shfl_xor(v[0], 1);
}

// ================= GEMV core: 8 cols/block, 3-deep DMA pipeline ==============
// Block = 8 cols x 16 m, 4 waves. Wave w owns cols {2w,2w+1} (all 16 m) and
// stages those 2 W rows + x rows 4w..4w+3 per 256-k slot (6 segs/wave/slot).
// 3-deep LDS buffers, steady-state s_waitcnt vmcnt(12) keeps 2 slots in
// flight across barriers (never drain mid-loop).
template<int KDIM>
__device__ __forceinline__ void gemv_core8(const float* __restrict__ A,
                                           const float* __restrict__ W,
                                           int cb, int w, int lane,
                                           float* sbuf, float* acc) {
    constexpr int NS = KDIM / 256;
    const float* wsrc0 = W + (size_t)(cb + 2 * w)     * KDIM + lane * 4;
    const float* wsrc1 = W + (size_t)(cb + 2 * w + 1) * KDIM + lane * 4;
    auto issue = [&](int s) {
        if (s >= NS) return;
        float* dst = sbuf + (s % 3) * 6144;
        gload_lds16(wsrc0 + s * 256, dst + (2 * w) * 256);
        gload_lds16(wsrc1 + s * 256, dst + (2 * w + 1) * 256);
        #pragma unroll
        for (int j = 0; j < 4; ++j) {
            int m = w * 4 + j;
            gload_lds16(A + (size_t)m * KDIM + s * 256 + lane * 4,
                        dst + 2048 + m * 256);
        }
    };
    issue(0); issue(1); issue(2);
    #pragma unroll 1
    for (int s = 0; s < NS; ++s) {
        int rem = NS - 1 - s;
        if (rem >= 2)      asm volatile("s_waitcnt vmcnt(12) lgkmcnt(0)" ::: "memory");
        else if (rem == 1) asm volatile("s_waitcnt vmcnt(6) lgkmcnt(0)" ::: "memory");
        else               asm volatile("s_waitcnt vmcnt(0) lgkmcnt(0)" ::: "memory");
        __builtin_amdgcn_s_barrier();
        const float* buf = sbuf + (s % 3) * 6144;
        float4 wr0 = *(const float4*)(buf + (2 * w) * 256 + lane * 4);
        float4 wr1 = *(const float4*)(buf + (2 * w + 1) * 256 + lane * 4);
        float4 xr[16];
        #pragma unroll
        for (int m = 0; m < 16; ++m)
            xr[m] = *(const float4*)(buf + 2048 + m * 256 + lane * 4);
        asm volatile("s_waitcnt lgkmcnt(0)" ::: "memory");
        __builtin_amdgcn_s_barrier();
        issue(s + 3);
        #pragma unroll
        for (int m = 0; m < 16; ++m) {
            acc[m*2]   = fmaf(wr0.x, xr[m].x, acc[m*2]);
            acc[m*2]   = fmaf(wr0.y, xr[m].y, acc[m*2]);
            acc[m*2]   = fmaf(wr0.z, xr[m].z, acc[m*2]);
            acc[m*2]   = fmaf(wr0.w, xr[m].w, acc[m*2]);
            acc[m*2+1] = fmaf(wr1.x, xr[m].x, acc[m*2+1]);
            acc[m*2+1] = fmaf(wr1.y, xr[m].y, acc[m*2+1]);
            acc[m*2+1] = fmaf(wr1.z, xr[m].z, acc[m*2+1]);
            acc[m*2+1] = fmaf(wr1.w, xr[m].w, acc[m*2+1]);
        }
    }
}

// ---------------- fused QKV GEMV ----------------
__global__ __launch_bounds__(256) void k_qkv(const float* __restrict__ Xn,
                                             const float* __restrict__ Wq,
                                             const float* __restrict__ Wk,
                                             const float* __restrict__ Wv,
                                             float* __restrict__ qws,
                                             float* __restrict__ kws,
                                             float* __restrict__ vws) {
    __shared__ float sbuf[3 * 6144];
    int tid = threadIdx.x, w = tid >> 6, lane = tid & 63;
    int b = blockIdx.x;                    // 0..767
    int sel = b >> 8;                      // 256 blocks per matrix
    int cb = (b & 255) * 8;
    const float* W = (sel == 0) ? Wq : (sel == 1) ? Wk : Wv;
    float* dst = (sel == 0) ? qws : (sel == 1) ? kws : vws;
    float acc[32];
    #pragma unroll
    for (int i = 0; i < 32; ++i) acc[i] = 0.f;
    gemv_core8<2048>(Xn, W, cb, w, lane, sbuf, acc);
    fold32(acc, lane);
    if ((lane & 1) == 0) {
        int idx = (lane >> 1) & 31;
        int m = idx >> 1, c = idx & 1;
        int gcol = cb + 2 * w + c;
        int hh = gcol >> 7, d = gcol & 127;
        dst[(((size_t)hh * 16 + m) << 7) + d] = acc[0];
    }
}

// ---------------- Wup GEMV + gelu ----------------
__device__ __forceinline__ float gelu_exact(float x) {
    return 0.5f * x * (1.0f + erff(x * 0.7071067811865475f));
}

__global__ __launch_bounds__(256) void k_up(const float* __restrict__ A,
                                            const float* __restrict__ W,
                                            float* __restrict__ out) {
    __shared__ float sbuf[3 * 6144];
    int tid = threadIdx.x, w = tid >> 6, lane = tid & 63;
    int cb = blockIdx.x * 8;               // 1024 blocks
    float acc[32];
    #pragma unroll
    for (int i = 0; i < 32; ++i) acc[i] = 0.f;
    gemv_core8<2048>(A, W, cb, w, lane, sbuf, acc);
    fold32(acc, lane);
    if ((lane & 1) == 0) {
        int idx = (lane >> 1) & 31;
        int m = idx >> 1, c = idx & 1;
        out[(size_t)m * FFN + cb + 2 * w + c] = gelu_exact(acc[0]);
    }
}

// ---------------- GEMV + residual ----------------
template<int KDIM>
__global__ __launch_bounds__(256) void k_resid(const float* __restrict__ A,
                                               const float* __restrict__ W,
                                               const float* __restrict__ R,
                                               float* __restrict__ out) {
    __shared__ float sbuf[3 * 6144];
    int tid = threadIdx.x, w = tid >> 6, lane = tid & 63;
    int cb = blockIdx.x * 8;               // 256 blocks
    float acc[32];
    #pragma unroll
    for (int i = 0; i < 32; ++i) acc[i] = 0.f;
    gemv_core8<KDIM>(A, W, cb, w, lane, sbuf, acc);
    fold32(acc, lane);
    if ((lane & 1) == 0) {
        int idx = (lane >> 1) & 31;
        int m = idx >> 1, c = idx & 1;
        int col = cb + 2 * w + c;
        out[(size_t)m * NDIM + col] = R[(size_t)m * NDIM + col] + acc[0];
    }
}

// ---------------- LayerNorm: one block per row ----------------
__global__ __launch_bounds__(256) void k_ln(const float* __restrict__ X,
                                            const float* __restrict__ g,
                                            const float* __restrict__ b,
                                            float* __restrict__ out) {
    int row = blockIdx.x, tid = threadIdx.x;
    const float4* xp = (const float4*)(X + (size_t)row * NDIM);
    float4 v0 = xp[tid], v1 = xp[tid + 256];
    float s = v0.x + v0.y + v0.z + v0.w + v1.x + v1.y + v1.z + v1.w;
    float q = v0.x*v0.x + v0.y*v0.y + v0.z*v0.z + v0.w*v0.w
            + v1.x*v1.x + v1.y*v1.y + v1.z*v1.z + v1.w*v1.w;
    #pragma unroll
    for (int o = 32; o; o >>= 1) { s += __shfl_xor(s, o); q += __shfl_xor(q, o); }
    __shared__ float ls[4], lq[4];
    int wid = tid >> 6, lane = tid & 63;
    if (lane == 0) { ls[wid] = s; lq[wid] = q; }
    __syncthreads();
    s = ls[0] + ls[1] + ls[2] + ls[3];
    q = lq[0] + lq[1] + lq[2] + lq[3];
    float mu  = s * (1.f / NDIM);
    float var = q * (1.f / NDIM) - mu * mu;
    float rs  = rsqrtf(var + LN_EPS);
    float4 g0 = ((const float4*)g)[tid], g1 = ((const float4*)g)[tid + 256];
    float4 b0 = ((const float4*)b)[tid], b1 = ((const float4*)b)[tid + 256];
    float4 o0, o1;
    o0.x = (v0.x - mu) * rs * g0.x + b0.x;  o0.y = (v0.y - mu) * rs * g0.y + b0.y;
    o0.z = (v0.z - mu) * rs * g0.z + b0.z;  o0.w = (v0.w - mu) * rs * g0.w + b0.w;
    o1.x = (v1.x - mu) * rs * g1.x + b1.x;  o1.y = (v1.y - mu) * rs * g1.y + b1.y;
    o1.z = (v1.z - mu) * rs * g1.z + b1.z;  o1.w = (v1.w - mu) * rs * g1.w + b1.w;
    float4* op = (float4*)(out + (size_t)row * NDIM);
    op[tid] = o0; op[tid + 256] = o1;
}

// ---------------- attention: 4-deep DMA pipeline, q in registers -------------
// Block = (head, 128-row chunk), 4 waves. K/V stream through 4-deep LDS
// buffers via global_load_lds; steady-state s_waitcnt vmcnt(6) keeps 3 slots
// (2KB/wave each) in flight -> lead time ~3 slots of compute ~ HBM latency.
__global__ __launch_bounds__(256, 2) void k_attn(const float* __restrict__ cacheK,
                                                 const float* __restrict__ cacheV,
                                                 const float* __restrict__ qws,
                                                 const float* __restrict__ kws,
                                                 const float* __restrict__ vws,
                                                 float* __restrict__ part,   // [16h][65c][16m][128d]
                                                 float* __restrict__ ms) {   // [16h][65c][16m][2]
    __shared__ float s_k[4][2080];   // 16-row tile: pair j (2 rows) at float 260*j
    __shared__ float s_v[4][2080];
    __shared__ float s_p[16][132];   // scores [m][t] (wave-private by row)
    int bid = blockIdx.x;
    int h = bid / NCH, c = bid % NCH;
    int nT = (c < NCH - 1) ? TC : M_TOK;
    int NST = nT >> 4;               // 8 full subtiles, or 1 for the tail chunk
    const float* Kb = (c < NCH - 1) ? cacheK + ((size_t)h * MAXLEN + (size_t)c * TC) * DHEAD
                                    : kws + (size_t)h * M_TOK * DHEAD;
    const float* Vb = (c < NCH - 1) ? cacheV + ((size_t)h * MAXLEN + (size_t)c * TC) * DHEAD
                                    : vws + (size_t)h * M_TOK * DHEAD;
    int tid = threadIdx.x, w = tid >> 6, lane = tid & 63;
    int tloc = lane & 15, ds = lane >> 4;

    // hoist q into registers: wave's 4 m rows, lane's ds-slice (32 floats)
    float4 qreg[4][8];
    {
        const float4* qp = (const float4*)(qws + (size_t)h * M_TOK * DHEAD);
        #pragma unroll
        for (int mm = 0; mm < 4; ++mm) {
            #pragma unroll
            for (int i = 0; i < 8; ++i)
                qreg[mm][i] = qp[(size_t)(w * 4 + mm) * 32 + ds * 8 + i];
        }
    }
    // drain q loads BEFORE issuing DMA so no later wait drains the pipeline
    asm volatile("s_waitcnt vmcnt(0)" ::: "memory");

    // slot [0,NST) = K tile, [NST,2NST) = V tile; wave stages pairs 2w, 2w+1
    auto issue = [&](int slot) {
        if (slot >= 2 * NST) return;
        const float* src; float* dst;
        if (slot < NST) { src = Kb + (size_t)slot * 16 * DHEAD; dst = s_k[slot & 3]; }
        else { int j = slot - NST; src = Vb + (size_t)j * 16 * DHEAD; dst = s_v[j & 3]; }
        #pragma unroll
        for (int k = 0; k < 2; ++k) {
            int j = w * 2 + k;
            gload_lds16(src + j * 256 + lane * 4, dst + j * 260);
        }
    };

    issue(0); issue(1); issue(2); issue(3);
    const int lastSlot = 2 * NST - 1;

    #define WAIT_LADDER(s)                                                          \
        { int rem = lastSlot - (s);                                                 \
          if (rem >= 3)      asm volatile("s_waitcnt vmcnt(6) lgkmcnt(0)" ::: "memory"); \
          else if (rem == 2) asm volatile("s_waitcnt vmcnt(4) lgkmcnt(0)" ::: "memory"); \
          else if (rem == 1) asm volatile("s_waitcnt vmcnt(2) lgkmcnt(0)" ::: "memory"); \
          else               asm volatile("s_waitcnt vmcnt(0) lgkmcnt(0)" ::: "memory"); }

    // ================= K steps: QK^T =================
    for (int s = 0; s < NST; ++s) {
        WAIT_LADDER(s);
        __builtin_amdgcn_s_barrier();
        const float* kbase = s_k[s & 3] + (tloc >> 1) * 260 + (tloc & 1) * 128 + ds * 32;
        float4 kr[8];
        #pragma unroll
        for (int i = 0; i < 8; ++i) kr[i] = *(const float4*)(kbase + i * 4);
        asm volatile("s_waitcnt lgkmcnt(0)" ::: "memory");
        __builtin_amdgcn_s_barrier();
        issue(s + 4);
        #pragma unroll
        for (int mm = 0; mm < 4; ++mm) {
            float a0 = 0.f, a1 = 0.f, a2 = 0.f, a3 = 0.f;
            #pragma unroll
            for (int i = 0; i < 8; ++i) {
                a0 = fmaf(kr[i].x, qreg[mm][i].x, a0);
                a1 = fmaf(kr[i].y, qreg[mm][i].y, a1);
                a2 = fmaf(kr[i].z, qreg[mm][i].z, a2);
                a3 = fmaf(kr[i].w, qreg[mm][i].w, a3);
            }
            float s0 = (a0 + a1) + (a2 + a3);
            s0 += __shfl_xor(s0, 16);
            s0 += __shfl_xor(s0, 32);
            if (ds == 0) s_p[w * 4 + mm][s * 16 + tloc] = s0 * RSQRT_D;
        }
    }

    // ================= softmax (rows are wave-private) =================
    {
        int m2 = tid >> 4, tl = tid & 15;
        float mx = -1e30f;
        for (int t = tl; t < nT; t += 16) mx = fmaxf(mx, s_p[m2][t]);
        #pragma unroll
        for (int o = 8; o; o >>= 1) mx = fmaxf(mx, __shfl_xor(mx, o));
        float sm = 0.f;
        for (int t = tl; t < nT; t += 16) {
            float p = __expf(s_p[m2][t] - mx);
            s_p[m2][t] = p;
            sm += p;
        }
        #pragma unroll
        for (int o = 8; o; o >>= 1) sm += __shfl_xor(sm, o);
        if (tl == 0) {
            float* msp = ms + ((size_t)(h * NCH + c) * 16 + m2) * 2;
            msp[0] = mx; msp[1] = sm;
        }
    }

    // ================= V steps: PV =================
    float2 acc[4] = {{0.f,0.f},{0.f,0.f},{0.f,0.f},{0.f,0.f}};
    for (int j = 0; j < NST; ++j) {
        int s = NST + j;
        WAIT_LADDER(s);
        __builtin_amdgcn_s_barrier();
        float2 vr[16];
        const float* vbase = s_v[j & 3];
        #pragma unroll
        for (int r = 0; r < 16; ++r)
            vr[r] = *(const float2*)(vbase + (r >> 1) * 260 + (r & 1) * 128 + lane * 2);
        asm volatile("s_waitcnt lgkmcnt(0)" ::: "memory");
        __builtin_amdgcn_s_barrier();
        issue(s + 4);
        #pragma unroll
        for (int mm = 0; mm < 4; ++mm) {
            int m = w * 4 + mm;
            const float* prow = &s_p[m][j * 16];
            #pragma unroll
            for (int g4 = 0; g4 < 4; ++g4) {
                float4 p4 = *(const float4*)(prow + g4 * 4);
                acc[mm].x = fmaf(p4.x, vr[g4*4+0].x, acc[mm].x);
                acc[mm].y = fmaf(p4.x, vr[g4*4+0].y, acc[mm].y);
                acc[mm].x = fmaf(p4.y, vr[g4*4+1].x, acc[mm].x);
                acc[mm].y = fmaf(p4.y, vr[g4*4+1].y, acc[mm].y);
                acc[mm].x = fmaf(p4.z, vr[g4*4+2].x, acc[mm].x);
                acc[mm].y = fmaf(p4.z, vr[g4*4+2].y, acc[mm].y);
                acc[mm].x = fmaf(p4.w, vr[g4*4+3].x, acc[mm].x);
                acc[mm].y = fmaf(p4.w, vr[g4*4+3].y, acc[mm].y);
            }
        }
    }
    #undef WAIT_LADDER

    float* dp = part + (((size_t)(h * NCH + c) * 16) + w * 4) * DHEAD + 2 * lane;
    #pragma unroll
    for (int mm = 0; mm < 4; ++mm)
        *(float2*)(dp + (size_t)mm * DHEAD) = acc[mm];
}

// ---------------- combine chunk partials: block per (head, 16-d slice) -------
__global__ __launch_bounds__(256) void k_combine(const float* __restrict__ part,
                                                 const float* __restrict__ ms,
                                                 float* __restrict__ attnout) {
    __shared__ float s_scale[16][NCH + 3];
    int h = blockIdx.x >> 3, dblk = blockIdx.x & 7;
    int tid = threadIdx.x;
    {
        int cl = tid & 15, m = tid >> 4;
        float gmax = -1e30f;
        for (int c = cl; c < NCH; c += 16)
            gmax = fmaxf(gmax, ms[((size_t)(h * NCH + c) * 16 + m) * 2]);
        #pragma unroll
        for (int o = 8; o; o >>= 1) gmax = fmaxf(gmax, __shfl_xor(gmax, o));
        float denom = 0.f;
        for (int c = cl; c < NCH; c += 16) {
            const float* msp = ms + ((size_t)(h * NCH + c) * 16 + m) * 2;
            denom += msp[1] * __expf(msp[0] - gmax);
        }
        #pragma unroll
        for (int o = 8; o; o >>= 1) denom += __shfl_xor(denom, o);
        float inv = 1.f / denom;
        for (int c = cl; c < NCH; c += 16) {
            const float* msp = ms + ((size_t)(h * NCH + c) * 16 + m) * 2;
            s_scale[m][c] = __expf(msp[0] - gmax) * inv;
        }
    }
    __syncthreads();
    int m = tid >> 4, dd = tid & 15;
    int d = dblk * 16 + dd;
    const float* pp = part + ((size_t)h * NCH * 16 + m) * DHEAD + d;
    float acc = 0.f;
    #pragma unroll 4
    for (int c = 0; c < NCH; ++c)
        acc = fmaf(pp[(size_t)c * 16 * DHEAD], s_scale[m][c], acc);
    attnout[(size_t)m * NDIM + h * DHEAD + d] = acc;
}

// ---------------- launcher ----------------
extern "C" void kernel_launch(void* const* d_in, const int* in_sizes, int n_in,
                              void* d_out, int out_size, void* d_ws, size_t ws_size,
                              hipStream_t stream) {
    const float* X      = (const float*)d_in[0];
    const float* ln1_g  = (const float*)d_in[1];
    const float* ln1_b  = (const float*)d_in[2];
    const float* Wq     = (const float*)d_in[3];
    const float* Wk     = (const float*)d_in[4];
    const float* Wv     = (const float*)d_in[5];
    const float* Wo     = (const float*)d_in[6];
    const float* ln2_g  = (const float*)d_in[7];
    const float* ln2_b  = (const float*)d_in[8];
    const float* Wup    = (const float*)d_in[9];
    const float* Wdown  = (const float*)d_in[10];
    const float* cacheK = (const float*)d_in[11];
    const float* cacheV = (const float*)d_in[12];
    float* out = (float*)d_out;

    float* ws = (float*)d_ws;
    float* Xn1    = ws;                       // 32768
    float* qws    = Xn1 + 32768;              // 32768
    float* kws    = qws + 32768;              // 32768
    float* vws    = kws + 32768;              // 32768
    float* partb  = vws + 32768;              // 16*65*16*128 = 2129920
    float* msb    = partb + 2129920;          // 16*65*16*2   = 33280
    float* attn_o = msb + 33280;              // 32768
    float* X2     = attn_o + 32768;           // 32768
    float* Xn2    = X2 + 32768;               // 32768
    float* ffnh   = Xn2 + 32768;              // 131072

    k_ln<<<M_TOK, 256, 0, stream>>>(X, ln1_g, ln1_b, Xn1);
    k_qkv<<<768, 256, 0, stream>>>(Xn1, Wq, Wk, Wv, qws, kws, vws);
    k_attn<<<NHEAD * NCH, 256, 0, stream>>>(cacheK, cacheV, qws, kws, vws, partb, msb);
    k_combine<<<NHEAD * 8, 256, 0, stream>>>(partb, msb, attn_o);
    k_resid<2048><<<256, 256, 0, stream>>>(attn_o, Wo, X, X2);
    k_ln<<<M_TOK, 256, 0, stream>>>(X2, ln2_g, ln2_b, Xn2);
    k_up<<<1024, 256, 0, stream>>>(Xn2, Wup, ffnh);
    k_resid<8192><<<256, 256, 0, stream>>>(ffnh, Wdown, X2, out);
}

// Round 11
// 142.524 us; speedup vs baseline: 1.0173x; 1.0173x over previous
//
#include <hip/hip_runtime.h>
#include <hip/hip_bf16.h>
#include <math.h>

#define M_TOK 16
#define NDIM  2048
#define DHEAD 128
#define NHEAD 16
#define MAXLEN 8448
#define FFN   8192
#define TC    128
#define NCH   65   // 64 cache chunks of 128 + 1 chunk of the 16 new rows
#define LN_EPS 1e-5f
#define RSQRT_D 0.08838834764831845f  // 1/sqrt(128)

#define AS1 __attribute__((address_space(1)))
#define AS3 __attribute__((address_space(3)))

typedef float f4v __attribute__((ext_vector_type(4)));
typedef float f2v __attribute__((ext_vector_type(2)));

// async global->LDS DMA: lane i writes 16B at lds_base + i*16 (wave-uniform base)
__device__ __forceinline__ void gload_lds16(const float* g, float* l) {
    __builtin_amdgcn_global_load_lds((AS1 void*)g, (AS3 void*)l, 16, 0, 0);
}

// LDS byte offset of a __shared__-derived pointer (generic -> AS3 addrspacecast)
__device__ __forceinline__ uint32_t lds_off(const void* p) {
    return (uint32_t)(uintptr_t)(const AS3 void*)p;
}

// inline-asm LDS ops: invisible to the compiler's alias/waitcnt machinery, so
// it cannot insert its own vmcnt(0) drains against outstanding global_load_lds.
__device__ __forceinline__ f4v dsr_b128(uint32_t off) {
    f4v r; asm volatile("ds_read_b128 %0, %1" : "=v"(r) : "v"(off)); return r;
}
__device__ __forceinline__ f2v dsr_b64(uint32_t off) {
    f2v r; asm volatile("ds_read_b64 %0, %1" : "=v"(r) : "v"(off)); return r;
}
__device__ __forceinline__ float dsr_b32(uint32_t off) {
    float r; asm volatile("ds_read_b32 %0, %1" : "=v"(r) : "v"(off)); return r;
}
__device__ __forceinline__ void dsw_b32(uint32_t off, float v) {
    asm volatile("ds_write_b32 %0, %1" : : "v"(off), "v"(v));
}
#define LGKM0()  asm volatile("s_waitcnt lgkmcnt(0)" ::: "memory")
#define SCHED0() __builtin_amdgcn_sched_barrier(0)

// ================= fold reduce =================
template<int H>
__device__ __forceinline__ void fold_step(float* v, int lane, int o) {
    bool hi = (lane & o) != 0;
    #pragma unroll
    for (int i = 0; i < H; ++i) {
        float send = hi ? v[i] : v[i + H];
        float keep = hi ? v[i + H] : v[i];
        v[i] = keep + __shfl_xor(send, o);
    }
}

// 32 partials per lane -> lane L holds the all-lane sum of v[(L>>1)&31]
__device__ __forceinline__ void fold32(float* v, int lane) {
    fold_step<16>(v, lane, 32);
    fold_step<8>(v, lane, 16);
    fold_step<4>(v, lane, 8);
    fold_step<2>(v, lane, 4);
    fold_step<1>(v, lane, 2);
    v[0] += __shfl_xor(v[0], 1);
}

// ================= GEMV core: 8 cols/block, 3-deep DMA pipeline ==============
// R10 geometry; ALL staged-LDS reads are inline-asm so the counted vmcnt
// ladder is the only wait (compiler cannot drain the pipeline).
template<int KDIM>
__device__ __forceinline__ void gemv_core8(const float* __restrict__ A,
                                           const float* __restrict__ W,
                                           int cb, int w, int lane,
                                           float* sbuf, float* acc) {
    constexpr int NS = KDIM / 256;
    const float* wsrc0 = W + (size_t)(cb + 2 * w)     * KDIM + lane * 4;
    const float* wsrc1 = W + (size_t)(cb + 2 * w + 1) * KDIM + lane * 4;
    auto issue = [&](int s) {
        if (s >= NS) return;
        float* dst = sbuf + (s % 3) * 6144;
        gload_lds16(wsrc0 + s * 256, dst + (2 * w) * 256);
        gload_lds16(wsrc1 + s * 256, dst + (2 * w + 1) * 256);
        #pragma unroll
        for (int j = 0; j < 4; ++j) {
            int m = w * 4 + j;
            gload_lds16(A + (size_t)m * KDIM + s * 256 + lane * 4,
                        dst + 2048 + m * 256);
        }
    };
    issue(0); issue(1); issue(2);
    const uint32_t sb = lds_off(sbuf);
    #pragma unroll 1
    for (int s = 0; s < NS; ++s) {
        int rem = NS - 1 - s;
        if (rem >= 2)      asm volatile("s_waitcnt vmcnt(12)" ::: "memory");
        else if (rem == 1) asm volatile("s_waitcnt vmcnt(6)" ::: "memory");
        else               asm volatile("s_waitcnt vmcnt(0)" ::: "memory");
        __builtin_amdgcn_s_barrier();
        SCHED0();
        uint32_t b = sb + (uint32_t)((s % 3) * 6144) * 4u;
        f4v wr0 = dsr_b128(b + (uint32_t)((2 * w) * 256 + lane * 4) * 4u);
        f4v wr1 = dsr_b128(b + (uint32_t)((2 * w + 1) * 256 + lane * 4) * 4u);
        f4v xr[16];
        #pragma unroll
        for (int m = 0; m < 16; ++m)
            xr[m] = dsr_b128(b + (uint32_t)(2048 + m * 256 + lane * 4) * 4u);
        LGKM0();
        SCHED0();
        __builtin_amdgcn_s_barrier();
        issue(s + 3);
        #pragma unroll
        for (int m = 0; m < 16; ++m) {
            acc[m*2]   = fmaf(wr0.x, xr[m].x, acc[m*2]);
            acc[m*2]   = fmaf(wr0.y, xr[m].y, acc[m*2]);
            acc[m*2]   = fmaf(wr0.z, xr[m].z, acc[m*2]);
            acc[m*2]   = fmaf(wr0.w, xr[m].w, acc[m*2]);
            acc[m*2+1] = fmaf(wr1.x, xr[m].x, acc[m*2+1]);
            acc[m*2+1] = fmaf(wr1.y, xr[m].y, acc[m*2+1]);
            acc[m*2+1] = fmaf(wr1.z, xr[m].z, acc[m*2+1]);
            acc[m*2+1] = fmaf(wr1.w, xr[m].w, acc[m*2+1]);
        }
    }
}

// ---------------- fused QKV GEMV ----------------
__global__ __launch_bounds__(256) void k_qkv(const float* __restrict__ Xn,
                                             const float* __restrict__ Wq,
                                             const float* __restrict__ Wk,
                                             const float* __restrict__ Wv,
                                             float* __restrict__ qws,
                                             float* __restrict__ kws,
                                             float* __restrict__ vws) {
    __shared__ float sbuf[3 * 6144];
    int tid = threadIdx.x, w = tid >> 6, lane = tid & 63;
    int b = blockIdx.x;                    // 0..767
    int sel = b >> 8;                      // 256 blocks per matrix
    int cb = (b & 255) * 8;
    const float* W = (sel == 0) ? Wq : (sel == 1) ? Wk : Wv;
    float* dst = (sel == 0) ? qws : (sel == 1) ? kws : vws;
    float acc[32];
    #pragma unroll
    for (int i = 0; i < 32; ++i) acc[i] = 0.f;
    gemv_core8<2048>(Xn, W, cb, w, lane, sbuf, acc);
    fold32(acc, lane);
    if ((lane & 1) == 0) {
        int idx = (lane >> 1) & 31;
        int m = idx >> 1, c = idx & 1;
        int gcol = cb + 2 * w + c;
        int hh = gcol >> 7, d = gcol & 127;
        dst[(((size_t)hh * 16 + m) << 7) + d] = acc[0];
    }
}

// ---------------- Wup GEMV + gelu ----------------
__device__ __forceinline__ float gelu_exact(float x) {
    return 0.5f * x * (1.0f + erff(x * 0.7071067811865475f));
}

__global__ __launch_bounds__(256) void k_up(const float* __restrict__ A,
                                            const float* __restrict__ W,
                                            float* __restrict__ out) {
    __shared__ float sbuf[3 * 6144];
    int tid = threadIdx.x, w = tid >> 6, lane = tid & 63;
    int cb = blockIdx.x * 8;               // 1024 blocks
    float acc[32];
    #pragma unroll
    for (int i = 0; i < 32; ++i) acc[i] = 0.f;
    gemv_core8<2048>(A, W, cb, w, lane, sbuf, acc);
    fold32(acc, lane);
    if ((lane & 1) == 0) {
        int idx = (lane >> 1) & 31;
        int m = idx >> 1, c = idx & 1;
        out[(size_t)m * FFN + cb + 2 * w + c] = gelu_exact(acc[0]);
    }
}

// ---------------- GEMV + residual ----------------
template<int KDIM>
__global__ __launch_bounds__(256) void k_resid(const float* __restrict__ A,
                                               const float* __restrict__ W,
                                               const float* __restrict__ R,
                                               float* __restrict__ out) {
    __shared__ float sbuf[3 * 6144];
    int tid = threadIdx.x, w = tid >> 6, lane = tid & 63;
    int cb = blockIdx.x * 8;               // 256 blocks
    float acc[32];
    #pragma unroll
    for (int i = 0; i < 32; ++i) acc[i] = 0.f;
    gemv_core8<KDIM>(A, W, cb, w, lane, sbuf, acc);
    fold32(acc, lane);
    if ((lane & 1) == 0) {
        int idx = (lane >> 1) & 31;
        int m = idx >> 1, c = idx & 1;
        int col = cb + 2 * w + c;
        out[(size_t)m * NDIM + col] = R[(size_t)m * NDIM + col] + acc[0];
    }
}

// ---------------- LayerNorm: one block per row ----------------
__global__ __launch_bounds__(256) void k_ln(const float* __restrict__ X,
                                            const float* __restrict__ g,
                                            const float* __restrict__ b,
                                            float* __restrict__ out) {
    int row = blockIdx.x, tid = threadIdx.x;
    const float4* xp = (const float4*)(X + (size_t)row * NDIM);
    float4 v0 = xp[tid], v1 = xp[tid + 256];
    float s = v0.x + v0.y + v0.z + v0.w + v1.x + v1.y + v1.z + v1.w;
    float q = v0.x*v0.x + v0.y*v0.y + v0.z*v0.z + v0.w*v0.w
            + v1.x*v1.x + v1.y*v1.y + v1.z*v1.z + v1.w*v1.w;
    #pragma unroll
    for (int o = 32; o; o >>= 1) { s += __shfl_xor(s, o); q += __shfl_xor(q, o); }
    __shared__ float ls[4], lq[4];
    int wid = tid >> 6, lane = tid & 63;
    if (lane == 0) { ls[wid] = s; lq[wid] = q; }
    __syncthreads();
    s = ls[0] + ls[1] + ls[2] + ls[3];
    q = lq[0] + lq[1] + lq[2] + lq[3];
    float mu  = s * (1.f / NDIM);
    float var = q * (1.f / NDIM) - mu * mu;
    float rs  = rsqrtf(var + LN_EPS);
    float4 g0 = ((const float4*)g)[tid], g1 = ((const float4*)g)[tid + 256];
    float4 b0 = ((const float4*)b)[tid], b1 = ((const float4*)b)[tid + 256];
    float4 o0, o1;
    o0.x = (v0.x - mu) * rs * g0.x + b0.x;  o0.y = (v0.y - mu) * rs * g0.y + b0.y;
    o0.z = (v0.z - mu) * rs * g0.z + b0.z;  o0.w = (v0.w - mu) * rs * g0.w + b0.w;
    o1.x = (v1.x - mu) * rs * g1.x + b1.x;  o1.y = (v1.y - mu) * rs * g1.y + b1.y;
    o1.z = (v1.z - mu) * rs * g1.z + b1.z;  o1.w = (v1.w - mu) * rs * g1.w + b1.w;
    float4* op = (float4*)(out + (size_t)row * NDIM);
    op[tid] = o0; op[tid + 256] = o1;
}

// ---------------- attention: 4-deep DMA pipeline, asm LDS reads --------------
// Block = (head, 128-row chunk), 4 waves. K/V stream through 4-deep LDS
// buffers via global_load_lds; counted vmcnt ladder is the ONLY wait —
// all staged-LDS reads are inline asm so the compiler cannot drain.
__global__ __launch_bounds__(256, 2) void k_attn(const float* __restrict__ cacheK,
                                                 const float* __restrict__ cacheV,
                                                 const float* __restrict__ qws,
                                                 const float* __restrict__ kws,
                                                 const float* __restrict__ vws,
                                                 float* __restrict__ part,   // [16h][65c][16m][128d]
                                                 float* __restrict__ ms) {   // [16h][65c][16m][2]
    __shared__ float s_k[4][2080];   // 16-row tile: pair j (2 rows) at float 260*j
    __shared__ float s_v[4][2080];
    __shared__ float s_p[16][132];   // scores [m][t] (wave-private by row)
    int bid = blockIdx.x;
    int h = bid / NCH, c = bid % NCH;
    int nT = (c < NCH - 1) ? TC : M_TOK;
    int NST = nT >> 4;               // 8 full subtiles, or 1 for the tail chunk
    const float* Kb = (c < NCH - 1) ? cacheK + ((size_t)h * MAXLEN + (size_t)c * TC) * DHEAD
                                    : kws + (size_t)h * M_TOK * DHEAD;
    const float* Vb = (c < NCH - 1) ? cacheV + ((size_t)h * MAXLEN + (size_t)c * TC) * DHEAD
                                    : vws + (size_t)h * M_TOK * DHEAD;
    int tid = threadIdx.x, w = tid >> 6, lane = tid & 63;
    int tloc = lane & 15, ds = lane >> 4;

    // hoist q into registers: wave's 4 m rows, lane's ds-slice (32 floats)
    float4 qreg[4][8];
    {
        const float4* qp = (const float4*)(qws + (size_t)h * M_TOK * DHEAD);
        #pragma unroll
        for (int mm = 0; mm < 4; ++mm) {
            #pragma unroll
            for (int i = 0; i < 8; ++i)
                qreg[mm][i] = qp[(size_t)(w * 4 + mm) * 32 + ds * 8 + i];
        }
    }
    // drain q loads BEFORE issuing DMA so no later wait drains the pipeline
    asm volatile("s_waitcnt vmcnt(0)" ::: "memory");

    // slot [0,NST) = K tile, [NST,2NST) = V tile; wave stages pairs 2w, 2w+1
    auto issue = [&](int slot) {
        if (slot >= 2 * NST) return;
        const float* src; float* dst;
        if (slot < NST) { src = Kb + (size_t)slot * 16 * DHEAD; dst = s_k[slot & 3]; }
        else { int j = slot - NST; src = Vb + (size_t)j * 16 * DHEAD; dst = s_v[j & 3]; }
        #pragma unroll
        for (int k = 0; k < 2; ++k) {
            int j = w * 2 + k;
            gload_lds16(src + j * 256 + lane * 4, dst + j * 260);
        }
    };

    issue(0); issue(1); issue(2); issue(3);
    const int lastSlot = 2 * NST - 1;
    const uint32_t skb = lds_off(s_k);
    const uint32_t svb = lds_off(s_v);
    const uint32_t spb = lds_off(s_p);

    #define WAIT_LADDER(s)                                                     \
        { int rem = lastSlot - (s);                                            \
          if (rem >= 3)      asm volatile("s_waitcnt vmcnt(6)" ::: "memory");  \
          else if (rem == 2) asm volatile("s_waitcnt vmcnt(4)" ::: "memory");  \
          else if (rem == 1) asm volatile("s_waitcnt vmcnt(2)" ::: "memory");  \
          else               asm volatile("s_waitcnt vmcnt(0)" ::: "memory"); }

    // ================= K steps: QK^T =================
    for (int s = 0; s < NST; ++s) {
        WAIT_LADDER(s);
        __builtin_amdgcn_s_barrier();
        SCHED0();
        uint32_t kb = skb + (uint32_t)((s & 3) * 2080 +
                     (tloc >> 1) * 260 + (tloc & 1) * 128 + ds * 32) * 4u;
        f4v kr[8];
        #pragma unroll
        for (int i = 0; i < 8; ++i) kr[i] = dsr_b128(kb + i * 16);
        LGKM0();
        SCHED0();
        __builtin_amdgcn_s_barrier();
        issue(s + 4);
        #pragma unroll
        for (int mm = 0; mm < 4; ++mm) {
            float a0 = 0.f, a1 = 0.f, a2 = 0.f, a3 = 0.f;
            #pragma unroll
            for (int i = 0; i < 8; ++i) {
                a0 = fmaf(kr[i].x, qreg[mm][i].x, a0);
                a1 = fmaf(kr[i].y, qreg[mm][i].y, a1);
                a2 = fmaf(kr[i].z, qreg[mm][i].z, a2);
                a3 = fmaf(kr[i].w, qreg[mm][i].w, a3);
            }
            float s0 = (a0 + a1) + (a2 + a3);
            s0 += __shfl_xor(s0, 16);
            s0 += __shfl_xor(s0, 32);
            if (ds == 0)
                dsw_b32(spb + (uint32_t)((w * 4 + mm) * 132 + s * 16 + tloc) * 4u,
                        s0 * RSQRT_D);
        }
    }

    // ================= softmax (rows wave-private; asm s_p access) ===========
    LGKM0();   // own ds_writes complete (same-wave order, belt & braces)
    SCHED0();
    float sm_mx, sm_sum;
    int m2 = tid >> 4, tl = tid & 15;
    {
        uint32_t prow = spb + (uint32_t)(m2 * 132) * 4u;
        float mx = -1e30f;
        for (int t = tl; t < nT; t += 16) mx = fmaxf(mx, dsr_b32(prow + t * 4));
        LGKM0();
        #pragma unroll
        for (int o = 8; o; o >>= 1) mx = fmaxf(mx, __shfl_xor(mx, o));
        float sm = 0.f;
        for (int t = tl; t < nT; t += 16) {
            float p = __expf(dsr_b32(prow + t * 4) - mx);
            LGKM0();
            dsw_b32(prow + t * 4, p);
            sm += p;
        }
        #pragma unroll
        for (int o = 8; o; o >>= 1) sm += __shfl_xor(sm, o);
        sm_mx = mx; sm_sum = sm;   // stored to ms at epilogue (keep vmcnt clean)
    }
    LGKM0();
    SCHED0();

    // ================= V steps: PV =================
    float2 acc[4] = {{0.f,0.f},{0.f,0.f},{0.f,0.f},{0.f,0.f}};
    for (int j = 0; j < NST; ++j) {
        int s = NST + j;
        WAIT_LADDER(s);
        __builtin_amdgcn_s_barrier();
        SCHED0();
        uint32_t vb = svb + (uint32_t)((j & 3) * 2080) * 4u;
        f2v vr[16];
        #pragma unroll
        for (int r = 0; r < 16; ++r)
            vr[r] = dsr_b64(vb + (uint32_t)((r >> 1) * 260 + (r & 1) * 128 + lane * 2) * 4u);
        f4v p0[4], p1[4], p2[4], p3[4];
        #pragma unroll
        for (int mm = 0; mm < 4; ++mm) {
            uint32_t prow = spb + (uint32_t)((w * 4 + mm) * 132 + j * 16) * 4u;
            p0[mm] = dsr_b128(prow);
            p1[mm] = dsr_b128(prow + 16);
            p2[mm] = dsr_b128(prow + 32);
            p3[mm] = dsr_b128(prow + 48);
        }
        LGKM0();
        SCHED0();
        __builtin_amdgcn_s_barrier();
        issue(s + 4);
        #pragma unroll
        for (int mm = 0; mm < 4; ++mm) {
            acc[mm].x = fmaf(p0[mm].x, vr[0].x, acc[mm].x);
            acc[mm].y = fmaf(p0[mm].x, vr[0].y, acc[mm].y);
            acc[mm].x = fmaf(p0[mm].y, vr[1].x, acc[mm].x);
            acc[mm].y = fmaf(p0[mm].y, vr[1].y, acc[mm].y);
            acc[mm].x = fmaf(p0[mm].z, vr[2].x, acc[mm].x);
            acc[mm].y = fmaf(p0[mm].z, vr[2].y, acc[mm].y);
            acc[mm].x = fmaf(p0[mm].w, vr[3].x, acc[mm].x);
            acc[mm].y = fmaf(p0[mm].w, vr[3].y, acc[mm].y);
            acc[mm].x = fmaf(p1[mm].x, vr[4].x, acc[mm].x);
            acc[mm].y = fmaf(p1[mm].x, vr[4].y, acc[mm].y);
            acc[mm].x = fmaf(p1[mm].y, vr[5].x, acc[mm].x);
            acc[mm].y = fmaf(p1[mm].y, vr[5].y, acc[mm].y);
            acc[mm].x = fmaf(p1[mm].z, vr[6].x, acc[mm].x);
            acc[mm].y = fmaf(p1[mm].z, vr[6].y, acc[mm].y);
            acc[mm].x = fmaf(p1[mm].w, vr[7].x, acc[mm].x);
            acc[mm].y = fmaf(p1[mm].w, vr[7].y, acc[mm].y);
            acc[mm].x = fmaf(p2[mm].x, vr[8].x, acc[mm].x);
            acc[mm].y = fmaf(p2[mm].x, vr[8].y, acc[mm].y);
            acc[mm].x = fmaf(p2[mm].y, vr[9].x, acc[mm].x);
            acc[mm].y = fmaf(p2[mm].y, vr[9].y, acc[mm].y);
            acc[mm].x = fmaf(p2[mm].z, vr[10].x, acc[mm].x);
            acc[mm].y = fmaf(p2[mm].z, vr[10].y, acc[mm].y);
            acc[mm].x = fmaf(p2[mm].w, vr[11].x, acc[mm].x);
            acc[mm].y = fmaf(p2[mm].w, vr[11].y, acc[mm].y);
            acc[mm].x = fmaf(p3[mm].x, vr[12].x, acc[mm].x);
            acc[mm].y = fmaf(p3[mm].x, vr[12].y, acc[mm].y);
            acc[mm].x = fmaf(p3[mm].y, vr[13].x, acc[mm].x);
            acc[mm].y = fmaf(p3[mm].y, vr[13].y, acc[mm].y);
            acc[mm].x = fmaf(p3[mm].z, vr[14].x, acc[mm].x);
            acc[mm].y = fmaf(p3[mm].z, vr[14].y, acc[mm].y);
            acc[mm].x = fmaf(p3[mm].w, vr[15].x, acc[mm].x);
            acc[mm].y = fmaf(p3[mm].w, vr[15].y, acc[mm].y);
        }
    }
    #undef WAIT_LADDER

    // epilogue: partials + (max,sum) — after final vmcnt(0), vmem is clean
    float* dp = part + (((size_t)(h * NCH + c) * 16) + w * 4) * DHEAD + 2 * lane;
    #pragma unroll
    for (int mm = 0; mm < 4; ++mm)
        *(float2*)(dp + (size_t)mm * DHEAD) = acc[mm];
    if (tl == 0) {
        float* msp = ms + ((size_t)(h * NCH + c) * 16 + m2) * 2;
        msp[0] = sm_mx; msp[1] = sm_sum;
    }
}

// ---------------- combine chunk partials: block per (head, 16-d slice) -------
__global__ __launch_bounds__(256) void k_combine(const float* __restrict__ part,
                                                 const float* __restrict__ ms,
                                                 float* __restrict__ attnout) {
    __shared__ float s_scale[16][NCH + 3];
    int h = blockIdx.x >> 3, dblk = blockIdx.x & 7;
    int tid = threadIdx.x;
    {
        int cl = tid & 15, m = tid >> 4;
        float gmax = -1e30f;
        for (int c = cl; c < NCH; c += 16)
            gmax = fmaxf(gmax, ms[((size_t)(h * NCH + c) * 16 + m) * 2]);
        #pragma unroll
        for (int o = 8; o; o >>= 1) gmax = fmaxf(gmax, __shfl_xor(gmax, o));
        float denom = 0.f;
        for (int c = cl; c < NCH; c += 16) {
            const float* msp = ms + ((size_t)(h * NCH + c) * 16 + m) * 2;
            denom += msp[1] * __expf(msp[0] - gmax);
        }
        #pragma unroll
        for (int o = 8; o; o >>= 1) denom += __shfl_xor(denom, o);
        float inv = 1.f / denom;
        for (int c = cl; c < NCH; c += 16) {
            const float* msp = ms + ((size_t)(h * NCH + c) * 16 + m) * 2;
            s_scale[m][c] = __expf(msp[0] - gmax) * inv;
        }
    }
    __syncthreads();
    int m = tid >> 4, dd = tid & 15;
    int d = dblk * 16 + dd;
    const float* pp = part + ((size_t)h * NCH * 16 + m) * DHEAD + d;
    float acc = 0.f;
    #pragma unroll 4
    for (int c = 0; c < NCH; ++c)
        acc = fmaf(pp[(size_t)c * 16 * DHEAD], s_scale[m][c], acc);
    attnout[(size_t)m * NDIM + h * DHEAD + d] = acc;
}

// ---------------- launcher ----------------
extern "C" void kernel_launch(void* const* d_in, const int* in_sizes, int n_in,
                              void* d_out, int out_size, void* d_ws, size_t ws_size,
                              hipStream_t stream) {
    const float* X      = (const float*)d_in[0];
    const float* ln1_g  = (const float*)d_in[1];
    const float* ln1_b  = (const float*)d_in[2];
    const float* Wq     = (const float*)d_in[3];
    const float* Wk     = (const float*)d_in[4];
    const float* Wv     = (const float*)d_in[5];
    const float* Wo     = (const float*)d_in[6];
    const float* ln2_g  = (const float*)d_in[7];
    const float* ln2_b  = (const float*)d_in[8];
    const float* Wup    = (const float*)d_in[9];
    const float* Wdown  = (const float*)d_in[10];
    const float* cacheK = (const float*)d_in[11];
    const float* cacheV = (const float*)d_in[12];
    float* out = (float*)d_out;

    float* ws = (float*)d_ws;
    float* Xn1    = ws;                       // 32768
    float* qws    = Xn1 + 32768;              // 32768
    float* kws    = qws + 32768;              // 32768
    float* vws    = kws + 32768;              // 32768
    float* partb  = vws + 32768;              // 16*65*16*128 = 2129920
    float* msb    = partb + 2129920;          // 16*65*16*2   = 33280
    float* attn_o = msb + 33280;              // 32768
    float* X2     = attn_o + 32768;           // 32768
    float* Xn2    = X2 + 32768;               // 32768
    float* ffnh   = Xn2 + 32768;              // 131072

    k_ln<<<M_TOK, 256, 0, stream>>>(X, ln1_g, ln1_b, Xn1);
    k_qkv<<<768, 256, 0, stream>>>(Xn1, Wq, Wk, Wv, qws, kws, vws);
    k_attn<<<NHEAD * NCH, 256, 0, stream>>>(cacheK, cacheV, qws, kws, vws, partb, msb);
    k_combine<<<NHEAD * 8, 256, 0, stream>>>(partb, msb, attn_o);
    k_resid<2048><<<256, 256, 0, stream>>>(attn_o, Wo, X, X2);
    k_ln<<<M_TOK, 256, 0, stream>>>(X2, ln2_g, ln2_b, Xn2);
    k_up<<<1024, 256, 0, stream>>>(Xn2, Wup, ffnh);
    k_resid<8192><<<256, 256, 0, stream>>>(ffnh, Wdown, X2, out);
}

// Round 12
// 141.751 us; speedup vs baseline: 1.0228x; 1.0055x over previous
//
#include <hip/hip_runtime.h>
#include <hip/hip_bf16.h>
#include <math.h>

#define M_TOK 16
#define NDIM  2048
#define DHEAD 128
#define NHEAD 16
#define MAXLEN 8448
#define FFN   8192
#define TC    64
#define NCH   129  // 128 cache chunks of 64 + 1 chunk of the 16 new rows
#define LN_EPS 1e-5f
#define RSQRT_D 0.08838834764831845f  // 1/sqrt(128)

#define AS1 __attribute__((address_space(1)))
#define AS3 __attribute__((address_space(3)))

typedef float f4v __attribute__((ext_vector_type(4)));
typedef float f2v __attribute__((ext_vector_type(2)));
typedef short bf16x8 __attribute__((ext_vector_type(8)));

// async global->LDS DMA: lane i writes 16B at lds_base + i*16 (wave-uniform base)
__device__ __forceinline__ void gload_lds16(const float* g, float* l) {
    __builtin_amdgcn_global_load_lds((AS1 void*)g, (AS3 void*)l, 16, 0, 0);
}

__device__ __forceinline__ uint32_t lds_off(const void* p) {
    return (uint32_t)(uintptr_t)(const AS3 void*)p;
}

// inline-asm memory ops: invisible to compiler waitcnt machinery
__device__ __forceinline__ f4v dsr_b128(uint32_t off) {
    f4v r; asm volatile("ds_read_b128 %0, %1" : "=v"(r) : "v"(off)); return r;
}
__device__ __forceinline__ float dsr_b32(uint32_t off) {
    float r; asm volatile("ds_read_b32 %0, %1" : "=v"(r) : "v"(off)); return r;
}
__device__ __forceinline__ void dsw_b32(uint32_t off, float v) {
    asm volatile("ds_write_b32 %0, %1" : : "v"(off), "v"(v));
}
__device__ __forceinline__ f4v gload_b128(const float* p) {
    f4v r;
    asm volatile("global_load_dwordx4 %0, %1, off"
                 : "=v"(r) : "v"((unsigned long long)(uintptr_t)p));
    return r;
}
#define LGKM0()  asm volatile("s_waitcnt lgkmcnt(0)" ::: "memory")
#define VM0()    asm volatile("s_waitcnt vmcnt(0)" ::: "memory")
#define SCHED0() __builtin_amdgcn_sched_barrier(0)

// f32 -> bf16 with round-to-nearest-even
__device__ __forceinline__ short f2bf(float x) {
    unsigned u = __float_as_uint(x);
    unsigned r = u + 0x7fffu + ((u >> 16) & 1u);
    return (short)(r >> 16);
}

// ================= fold reduce =================
template<int H>
__device__ __forceinline__ void fold_step(float* v, int lane, int o) {
    bool hi = (lane & o) != 0;
    #pragma unroll
    for (int i = 0; i < H; ++i) {
        float send = hi ? v[i] : v[i + H];
        float keep = hi ? v[i + H] : v[i];
        v[i] = keep + __shfl_xor(send, o);
    }
}

__device__ __forceinline__ void fold32(float* v, int lane) {
    fold_step<16>(v, lane, 32);
    fold_step<8>(v, lane, 16);
    fold_step<4>(v, lane, 8);
    fold_step<2>(v, lane, 4);
    fold_step<1>(v, lane, 2);
    v[0] += __shfl_xor(v[0], 1);
}

// ================= GEMV core: 8 cols/block, 3-deep DMA pipeline (R11) ========
template<int KDIM>
__device__ __forceinline__ void gemv_core8(const float* __restrict__ A,
                                           const float* __restrict__ W,
                                           int cb, int w, int lane,
                                           float* sbuf, float* acc) {
    constexpr int NS = KDIM / 256;
    const float* wsrc0 = W + (size_t)(cb + 2 * w)     * KDIM + lane * 4;
    const float* wsrc1 = W + (size_t)(cb + 2 * w + 1) * KDIM + lane * 4;
    auto issue = [&](int s) {
        if (s >= NS) return;
        float* dst = sbuf + (s % 3) * 6144;
        gload_lds16(wsrc0 + s * 256, dst + (2 * w) * 256);
        gload_lds16(wsrc1 + s * 256, dst + (2 * w + 1) * 256);
        #pragma unroll
        for (int j = 0; j < 4; ++j) {
            int m = w * 4 + j;
            gload_lds16(A + (size_t)m * KDIM + s * 256 + lane * 4,
                        dst + 2048 + m * 256);
        }
    };
    issue(0); issue(1); issue(2);
    const uint32_t sb = lds_off(sbuf);
    #pragma unroll 1
    for (int s = 0; s < NS; ++s) {
        int rem = NS - 1 - s;
        if (rem >= 2)      asm volatile("s_waitcnt vmcnt(12)" ::: "memory");
        else if (rem == 1) asm volatile("s_waitcnt vmcnt(6)" ::: "memory");
        else               asm volatile("s_waitcnt vmcnt(0)" ::: "memory");
        __builtin_amdgcn_s_barrier();
        SCHED0();
        uint32_t b = sb + (uint32_t)((s % 3) * 6144) * 4u;
        f4v wr0 = dsr_b128(b + (uint32_t)((2 * w) * 256 + lane * 4) * 4u);
        f4v wr1 = dsr_b128(b + (uint32_t)((2 * w + 1) * 256 + lane * 4) * 4u);
        f4v xr[16];
        #pragma unroll
        for (int m = 0; m < 16; ++m)
            xr[m] = dsr_b128(b + (uint32_t)(2048 + m * 256 + lane * 4) * 4u);
        LGKM0();
        SCHED0();
        __builtin_amdgcn_s_barrier();
        issue(s + 3);
        #pragma unroll
        for (int m = 0; m < 16; ++m) {
            acc[m*2]   = fmaf(wr0.x, xr[m].x, acc[m*2]);
            acc[m*2]   = fmaf(wr0.y, xr[m].y, acc[m*2]);
            acc[m*2]   = fmaf(wr0.z, xr[m].z, acc[m*2]);
            acc[m*2]   = fmaf(wr0.w, xr[m].w, acc[m*2]);
            acc[m*2+1] = fmaf(wr1.x, xr[m].x, acc[m*2+1]);
            acc[m*2+1] = fmaf(wr1.y, xr[m].y, acc[m*2+1]);
            acc[m*2+1] = fmaf(wr1.z, xr[m].z, acc[m*2+1]);
            acc[m*2+1] = fmaf(wr1.w, xr[m].w, acc[m*2+1]);
        }
    }
}

// ---------------- fused QKV GEMV ----------------
__global__ __launch_bounds__(256) void k_qkv(const float* __restrict__ Xn,
                                             const float* __restrict__ Wq,
                                             const float* __restrict__ Wk,
                                             const float* __restrict__ Wv,
                                             float* __restrict__ qws,
                                             float* __restrict__ kws,
                                             float* __restrict__ vws) {
    __shared__ float sbuf[3 * 6144];
    int tid = threadIdx.x, w = tid >> 6, lane = tid & 63;
    int b = blockIdx.x;
    int sel = b >> 8;
    int cb = (b & 255) * 8;
    const float* W = (sel == 0) ? Wq : (sel == 1) ? Wk : Wv;
    float* dst = (sel == 0) ? qws : (sel == 1) ? kws : vws;
    float acc[32];
    #pragma unroll
    for (int i = 0; i < 32; ++i) acc[i] = 0.f;
    gemv_core8<2048>(Xn, W, cb, w, lane, sbuf, acc);
    fold32(acc, lane);
    if ((lane & 1) == 0) {
        int idx = (lane >> 1) & 31;
        int m = idx >> 1, c = idx & 1;
        int gcol = cb + 2 * w + c;
        int hh = gcol >> 7, d = gcol & 127;
        dst[(((size_t)hh * 16 + m) << 7) + d] = acc[0];
    }
}

// ---------------- Wup GEMV + gelu ----------------
__device__ __forceinline__ float gelu_exact(float x) {
    return 0.5f * x * (1.0f + erff(x * 0.7071067811865475f));
}

__global__ __launch_bounds__(256) void k_up(const float* __restrict__ A,
                                            const float* __restrict__ W,
                                            float* __restrict__ out) {
    __shared__ float sbuf[3 * 6144];
    int tid = threadIdx.x, w = tid >> 6, lane = tid & 63;
    int cb = blockIdx.x * 8;
    float acc[32];
    #pragma unroll
    for (int i = 0; i < 32; ++i) acc[i] = 0.f;
    gemv_core8<2048>(A, W, cb, w, lane, sbuf, acc);
    fold32(acc, lane);
    if ((lane & 1) == 0) {
        int idx = (lane >> 1) & 31;
        int m = idx >> 1, c = idx & 1;
        out[(size_t)m * FFN + cb + 2 * w + c] = gelu_exact(acc[0]);
    }
}

// ---------------- GEMV + residual ----------------
template<int KDIM>
__global__ __launch_bounds__(256) void k_resid(const float* __restrict__ A,
                                               const float* __restrict__ W,
                                               const float* __restrict__ R,
                                               float* __restrict__ out) {
    __shared__ float sbuf[3 * 6144];
    int tid = threadIdx.x, w = tid >> 6, lane = tid & 63;
    int cb = blockIdx.x * 8;
    float acc[32];
    #pragma unroll
    for (int i = 0; i < 32; ++i) acc[i] = 0.f;
    gemv_core8<KDIM>(A, W, cb, w, lane, sbuf, acc);
    fold32(acc, lane);
    if ((lane & 1) == 0) {
        int idx = (lane >> 1) & 31;
        int m = idx >> 1, c = idx & 1;
        int col = cb + 2 * w + c;
        out[(size_t)m * NDIM + col] = R[(size_t)m * NDIM + col] + acc[0];
    }
}

// ---------------- LayerNorm ----------------
__global__ __launch_bounds__(256) void k_ln(const float* __restrict__ X,
                                            const float* __restrict__ g,
                                            const float* __restrict__ b,
                                            float* __restrict__ out) {
    int row = blockIdx.x, tid = threadIdx.x;
    const float4* xp = (const float4*)(X + (size_t)row * NDIM);
    float4 v0 = xp[tid], v1 = xp[tid + 256];
    float s = v0.x + v0.y + v0.z + v0.w + v1.x + v1.y + v1.z + v1.w;
    float q = v0.x*v0.x + v0.y*v0.y + v0.z*v0.z + v0.w*v0.w
            + v1.x*v1.x + v1.y*v1.y + v1.z*v1.z + v1.w*v1.w;
    #pragma unroll
    for (int o = 32; o; o >>= 1) { s += __shfl_xor(s, o); q += __shfl_xor(q, o); }
    __shared__ float ls[4], lq[4];
    int wid = tid >> 6, lane = tid & 63;
    if (lane == 0) { ls[wid] = s; lq[wid] = q; }
    __syncthreads();
    s = ls[0] + ls[1] + ls[2] + ls[3];
    q = lq[0] + lq[1] + lq[2] + lq[3];
    float mu  = s * (1.f / NDIM);
    float var = q * (1.f / NDIM) - mu * mu;
    float rs  = rsqrtf(var + LN_EPS);
    float4 g0 = ((const float4*)g)[tid], g1 = ((const float4*)g)[tid + 256];
    float4 b0 = ((const float4*)b)[tid], b1 = ((const float4*)b)[tid + 256];
    float4 o0, o1;
    o0.x = (v0.x - mu) * rs * g0.x + b0.x;  o0.y = (v0.y - mu) * rs * g0.y + b0.y;
    o0.z = (v0.z - mu) * rs * g0.z + b0.z;  o0.w = (v0.w - mu) * rs * g0.w + b0.w;
    o1.x = (v1.x - mu) * rs * g1.x + b1.x;  o1.y = (v1.y - mu) * rs * g1.y + b1.y;
    o1.z = (v1.z - mu) * rs * g1.z + b1.z;  o1.w = (v1.w - mu) * rs * g1.w + b1.w;
    float4* op = (float4*)(out + (size_t)row * NDIM);
    op[tid] = o0; op[tid + 256] = o1;
}

// ---------------- attention: MFMA bf16, bulk-staged K/V ----------------
// Block = (head, 64-row chunk), 4 waves. K,V staged once (swizzled source so
// fragment reads are ~conflict-free). QK^T and PV via mfma_f32_16x16x32_bf16.
// C/D map (m89): col=lane&15, row=(lane>>4)*4+reg. A/B k-permutation cancels
// because q/K (and P/V) fragments use identical (lane,elem)->k addressing.
__global__ __launch_bounds__(256) void k_attn(const float* __restrict__ cacheK,
                                              const float* __restrict__ cacheV,
                                              const float* __restrict__ qws,
                                              const float* __restrict__ kws,
                                              const float* __restrict__ vws,
                                              float* __restrict__ part,   // [16h][129c][16m][128d]
                                              float* __restrict__ ms) {   // [16h][129c][16m][2]
    __shared__ float s_k[TC * DHEAD];   // 32 KB, XOR-swizzled content
    __shared__ float s_v[TC * DHEAD];   // 32 KB, XOR-swizzled content
    __shared__ float s_p[16 * 68];      // scores [m][t], stride 68
    int bid = blockIdx.x;
    int h = bid / NCH, c = bid % NCH;
    int nT = (c < NCH - 1) ? TC : M_TOK;
    bool full = (nT == TC);
    int nSeg = nT >> 1;                 // 1KB segments (2 rows each)
    const float* Kb = (c < NCH - 1) ? cacheK + ((size_t)h * MAXLEN + (size_t)c * TC) * DHEAD
                                    : kws + (size_t)h * M_TOK * DHEAD;
    const float* Vb = (c < NCH - 1) ? cacheV + ((size_t)h * MAXLEN + (size_t)c * TC) * DHEAD
                                    : vws + (size_t)h * M_TOK * DHEAD;
    int tid = threadIdx.x, w = tid >> 6, lane = tid & 63;
    int g = lane >> 4;

    // ---- issue K DMA (source pre-swizzled: lds[b] = K[b ^ ((row&7)<<4)]) ----
    #pragma unroll
    for (int k = 0; k < 8; ++k) {
        int j = w + 4 * k;
        if (j < nSeg) {
            int b = j * 1024 + lane * 16;                 // dst byte (linear)
            int src = b ^ (((b >> 9) & 7) << 4);
            gload_lds16(Kb + (src >> 2), s_k + j * 256);
        }
    }

    // ---- q loads (asm, invisible to compiler waitcnt) ----
    int m_l = lane & 15;
    const float* qbase = qws + (size_t)h * M_TOK * DHEAD + (size_t)m_l * DHEAD;
    f4v qlo[4], qhi[4];
    #pragma unroll
    for (int blk = 0; blk < 4; ++blk) {
        qlo[blk] = gload_b128(qbase + blk * 32 + g * 4);
        qhi[blk] = gload_b128(qbase + blk * 32 + g * 4 + 16);
    }
    VM0();     // K staged + q in regs; V not yet issued
    SCHED0();

    // cvt q -> A fragments (elems 0-3: k-lo group, 4-7: k-hi group)
    bf16x8 qf[4];
    #pragma unroll
    for (int blk = 0; blk < 4; ++blk) {
        qf[blk][0] = f2bf(qlo[blk].x); qf[blk][1] = f2bf(qlo[blk].y);
        qf[blk][2] = f2bf(qlo[blk].z); qf[blk][3] = f2bf(qlo[blk].w);
        qf[blk][4] = f2bf(qhi[blk].x); qf[blk][5] = f2bf(qhi[blk].y);
        qf[blk][6] = f2bf(qhi[blk].z); qf[blk][7] = f2bf(qhi[blk].w);
    }

    // ---- issue V DMA (stays in flight through QK^T + softmax) ----
    #pragma unroll
    for (int k = 0; k < 8; ++k) {
        int j = w + 4 * k;
        if (j < nSeg) {
            int b = j * 1024 + lane * 16;
            int src = b ^ (((b >> 9) & 7) << 4);
            gload_lds16(Vb + (src >> 2), s_v + j * 256);
        }
    }
    __builtin_amdgcn_s_barrier();   // all waves' K staged

    const uint32_t skb = lds_off(s_k);
    const uint32_t svb = lds_off(s_v);
    const uint32_t spb = lds_off(s_p);

    // ================= QK^T: wave w computes t-tile [w*16, w*16+16) ==========
    int t0 = w * 16;
    if (t0 < nT) {
        int trow = t0 + (lane & 15);
        uint32_t xo = (uint32_t)((trow & 7) << 4);
        f4v klo[4], khi[4];
        #pragma unroll
        for (int blk = 0; blk < 4; ++blk) {
            uint32_t base = (uint32_t)(trow * 512 + blk * 128 + g * 16);
            klo[blk] = dsr_b128(skb + ((base)      ^ xo));
            khi[blk] = dsr_b128(skb + ((base + 64) ^ xo));
        }
        LGKM0();
        SCHED0();
        f4v accS = {0.f, 0.f, 0.f, 0.f};
        #pragma unroll
        for (int blk = 0; blk < 4; ++blk) {
            bf16x8 bk;
            bk[0] = f2bf(klo[blk].x); bk[1] = f2bf(klo[blk].y);
            bk[2] = f2bf(klo[blk].z); bk[3] = f2bf(klo[blk].w);
            bk[4] = f2bf(khi[blk].x); bk[5] = f2bf(khi[blk].y);
            bk[6] = f2bf(khi[blk].z); bk[7] = f2bf(khi[blk].w);
            accS = __builtin_amdgcn_mfma_f32_16x16x32_bf16(qf[blk], bk, accS, 0, 0, 0);
        }
        // D: S[m=(lane>>4)*4+reg][t=t0+(lane&15)]
        #pragma unroll
        for (int r = 0; r < 4; ++r) {
            int m = g * 4 + r;
            dsw_b32(spb + (uint32_t)((m * 68 + t0 + (lane & 15)) * 4), accS[r] * RSQRT_D);
        }
    }
    LGKM0();
    __builtin_amdgcn_s_barrier();

    // ================= softmax (thread = (m2, tl); 16 lanes per row) =========
    int m2 = tid >> 4, tl = tid & 15;
    float sm_mx, sm_sum;
    {
        uint32_t prow = spb + (uint32_t)(m2 * 68 * 4);
        float r0 = dsr_b32(prow + (uint32_t)(tl * 4));
        float r1 = -1e30f, r2 = -1e30f, r3 = -1e30f;
        if (full) {
            r1 = dsr_b32(prow + (uint32_t)((tl + 16) * 4));
            r2 = dsr_b32(prow + (uint32_t)((tl + 32) * 4));
            r3 = dsr_b32(prow + (uint32_t)((tl + 48) * 4));
        }
        LGKM0();
        SCHED0();
        float mx = fmaxf(fmaxf(r0, r1), fmaxf(r2, r3));
        #pragma unroll
        for (int o = 8; o; o >>= 1) mx = fmaxf(mx, __shfl_xor(mx, o));
        float p0 = __expf(r0 - mx), sum = p0;
        dsw_b32(prow + (uint32_t)(tl * 4), p0);
        if (full) {
            float p1 = __expf(r1 - mx), p2 = __expf(r2 - mx), p3 = __expf(r3 - mx);
            sum += p1 + p2 + p3;
            dsw_b32(prow + (uint32_t)((tl + 16) * 4), p1);
            dsw_b32(prow + (uint32_t)((tl + 32) * 4), p2);
            dsw_b32(prow + (uint32_t)((tl + 48) * 4), p3);
        }
        #pragma unroll
        for (int o = 8; o; o >>= 1) sum += __shfl_xor(sum, o);
        sm_mx = mx; sm_sum = sum;
    }
    LGKM0();
    VM0();       // V fully staged
    __builtin_amdgcn_s_barrier();

    // tail chunk: zero V rows [16,32) and p cols [16,32) so PV's 32-t MFMA is safe
    if (!full) {
        for (int i = tid; i < 16 * 128; i += 256) {
            int r = 16 + (i >> 7), dd = i & 127;
            dsw_b32(svb + (uint32_t)((r * 512 + dd * 4) ^ ((r & 7) << 4)), 0.f);
        }
        { int m = tid >> 4, t = 16 + (tid & 15);
          dsw_b32(spb + (uint32_t)((m * 68 + t) * 4), 0.f); }
        LGKM0();
        __builtin_amdgcn_s_barrier();
    }

    // ================= PV: wave w covers d-cols [w*32, w*32+32) ==============
    f4v accO0 = {0.f,0.f,0.f,0.f}, accO1 = {0.f,0.f,0.f,0.f};
    int dc0 = w * 32 + (lane & 15);
    int nTC = (nT + 31) >> 5;
    #pragma unroll
    for (int tc = 0; tc < 2; ++tc) {
        if (tc >= nTC) break;
        int m = lane & 15;
        f4v plo = dsr_b128(spb + (uint32_t)((m * 68 + tc * 32 + g * 4) * 4));
        f4v phi = dsr_b128(spb + (uint32_t)((m * 68 + tc * 32 + g * 4 + 16) * 4));
        float va[8], vb_[8];
        #pragma unroll
        for (int half = 0; half < 2; ++half) {
            #pragma unroll
            for (int jj = 0; jj < 4; ++jj) {
                int t = tc * 32 + g * 4 + jj + half * 16;
                uint32_t xo = (uint32_t)((t & 7) << 4);
                va[half*4+jj]  = dsr_b32(svb + ((uint32_t)(t * 512 + dc0 * 4)        ^ xo));
                vb_[half*4+jj] = dsr_b32(svb + ((uint32_t)(t * 512 + (dc0+16) * 4)   ^ xo));
            }
        }
        LGKM0();
        SCHED0();
        bf16x8 pa;
        pa[0] = f2bf(plo.x); pa[1] = f2bf(plo.y); pa[2] = f2bf(plo.z); pa[3] = f2bf(plo.w);
        pa[4] = f2bf(phi.x); pa[5] = f2bf(phi.y); pa[6] = f2bf(phi.z); pa[7] = f2bf(phi.w);
        bf16x8 v0, v1;
        #pragma unroll
        for (int j = 0; j < 8; ++j) { v0[j] = f2bf(va[j]); v1[j] = f2bf(vb_[j]); }
        accO0 = __builtin_amdgcn_mfma_f32_16x16x32_bf16(pa, v0, accO0, 0, 0, 0);
        accO1 = __builtin_amdgcn_mfma_f32_16x16x32_bf16(pa, v1, accO1, 0, 0, 0);
    }

    // epilogue: O[m=(g*4+r)][d] ; partials + (max,sum)
    float* pb = part + ((size_t)(h * NCH + c) * 16) * DHEAD;
    #pragma unroll
    for (int r = 0; r < 4; ++r) {
        int m = g * 4 + r;
        pb[(size_t)m * DHEAD + dc0]      = accO0[r];
        pb[(size_t)m * DHEAD + dc0 + 16] = accO1[r];
    }
    if (tl == 0) {
        float* msp = ms + ((size_t)(h * NCH + c) * 16 + m2) * 2;
        msp[0] = sm_mx; msp[1] = sm_sum;
    }
}

// ---------------- combine chunk partials ----------------
__global__ __launch_bounds__(256) void k_combine(const float* __restrict__ part,
                                                 const float* __restrict__ ms,
                                                 float* __restrict__ attnout) {
    __shared__ float s_scale[16][NCH + 3];
    int h = blockIdx.x >> 3, dblk = blockIdx.x & 7;
    int tid = threadIdx.x;
    {
        int cl = tid & 15, m = tid >> 4;
        float gmax = -1e30f;
        for (int c = cl; c < NCH; c += 16)
            gmax = fmaxf(gmax, ms[((size_t)(h * NCH + c) * 16 + m) * 2]);
        #pragma unroll
        for (int o = 8; o; o >>= 1) gmax = fmaxf(gmax, __shfl_xor(gmax, o));
        float denom = 0.f;
        for (int c = cl; c < NCH; c += 16) {
            const float* msp = ms + ((size_t)(h * NCH + c) * 16 + m) * 2;
            denom += msp[1] * __expf(msp[0] - gmax);
        }
        #pragma unroll
        for (int o = 8; o; o >>= 1) denom += __shfl_xor(denom, o);
        float inv = 1.f / denom;
        for (int c = cl; c < NCH; c += 16) {
            const float* msp = ms + ((size_t)(h * NCH + c) * 16 + m) * 2;
            s_scale[m][c] = __expf(msp[0] - gmax) * inv;
        }
    }
    __syncthreads();
    int m = tid >> 4, dd = tid & 15;
    int d = dblk * 16 + dd;
    const float* pp = part + ((size_t)h * NCH * 16 + m) * DHEAD + d;
    float acc = 0.f;
    #pragma unroll 4
    for (int c = 0; c < NCH; ++c)
        acc = fmaf(pp[(size_t)c * 16 * DHEAD], s_scale[m][c], acc);
    attnout[(size_t)m * NDIM + h * DHEAD + d] = acc;
}

// ---------------- launcher ----------------
extern "C" void kernel_launch(void* const* d_in, const int* in_sizes, int n_in,
                              void* d_out, int out_size, void* d_ws, size_t ws_size,
                              hipStream_t stream) {
    const float* X      = (const float*)d_in[0];
    const float* ln1_g  = (const float*)d_in[1];
    const float* ln1_b  = (const float*)d_in[2];
    const float* Wq     = (const float*)d_in[3];
    const float* Wk     = (const float*)d_in[4];
    const float* Wv     = (const float*)d_in[5];
    const float* Wo     = (const float*)d_in[6];
    const float* ln2_g  = (const float*)d_in[7];
    const float* ln2_b  = (const float*)d_in[8];
    const float* Wup    = (const float*)d_in[9];
    const float* Wdown  = (const float*)d_in[10];
    const float* cacheK = (const float*)d_in[11];
    const float* cacheV = (const float*)d_in[12];
    float* out = (float*)d_out;

    float* ws = (float*)d_ws;
    float* Xn1    = ws;                       // 32768
    float* qws    = Xn1 + 32768;              // 32768
    float* kws    = qws + 32768;              // 32768
    float* vws    = kws + 32768;              // 32768
    float* partb  = vws + 32768;              // 16*129*16*128 = 4227072
    float* msb    = partb + 4227072;          // 16*129*16*2   = 66048
    float* attn_o = msb + 66048;              // 32768
    float* X2     = attn_o + 32768;           // 32768
    float* Xn2    = X2 + 32768;               // 32768
    float* ffnh   = Xn2 + 32768;              // 131072

    k_ln<<<M_TOK, 256, 0, stream>>>(X, ln1_g, ln1_b, Xn1);
    k_qkv<<<768, 256, 0, stream>>>(Xn1, Wq, Wk, Wv, qws, kws, vws);
    k_attn<<<NHEAD * NCH, 256, 0, stream>>>(cacheK, cacheV, qws, kws, vws, partb, msb);
    k_combine<<<NHEAD * 8, 256, 0, stream>>>(partb, msb, attn_o);
    k_resid<2048><<<256, 256, 0, stream>>>(attn_o, Wo, X, X2);
    k_ln<<<M_TOK, 256, 0, stream>>>(X2, ln2_g, ln2_b, Xn2);
    k_up<<<1024, 256, 0, stream>>>(Xn2, Wup, ffnh);
    k_resid<8192><<<256, 256, 0, stream>>>(ffnh, Wdown, X2, out);
}

// Round 13
// 138.928 us; speedup vs baseline: 1.0436x; 1.0203x over previous
//
#include <hip/hip_runtime.h>
#include <hip/hip_bf16.h>
#include <math.h>

#define M_TOK 16
#define NDIM  2048
#define DHEAD 128
#define NHEAD 16
#define MAXLEN 8448
#define FFN   8192
#define TC    64
#define NCH   129  // 128 cache chunks of 64 + 1 chunk of the 16 new rows
#define LN_EPS 1e-5f
#define RSQRT_D 0.08838834764831845f  // 1/sqrt(128)

#define AS1 __attribute__((address_space(1)))
#define AS3 __attribute__((address_space(3)))

typedef float f4v __attribute__((ext_vector_type(4)));
typedef float f2v __attribute__((ext_vector_type(2)));
typedef short bf16x8 __attribute__((ext_vector_type(8)));

__device__ __forceinline__ void gload_lds16(const float* g, float* l) {
    __builtin_amdgcn_global_load_lds((AS1 void*)g, (AS3 void*)l, 16, 0, 0);
}
__device__ __forceinline__ uint32_t lds_off(const void* p) {
    return (uint32_t)(uintptr_t)(const AS3 void*)p;
}
__device__ __forceinline__ f4v dsr_b128(uint32_t off) {
    f4v r; asm volatile("ds_read_b128 %0, %1" : "=v"(r) : "v"(off)); return r;
}
__device__ __forceinline__ float dsr_b32(uint32_t off) {
    float r; asm volatile("ds_read_b32 %0, %1" : "=v"(r) : "v"(off)); return r;
}
__device__ __forceinline__ void dsw_b32(uint32_t off, float v) {
    asm volatile("ds_write_b32 %0, %1" : : "v"(off), "v"(v));
}
__device__ __forceinline__ f4v gload_b128(const float* p) {
    f4v r;
    asm volatile("global_load_dwordx4 %0, %1, off"
                 : "=v"(r) : "v"((unsigned long long)(uintptr_t)p));
    return r;
}
template<int OFF>
__device__ __forceinline__ f4v gload_off(const float* p) {
    f4v r;
    asm volatile("global_load_dwordx4 %0, %1, off offset:%2"
                 : "=v"(r) : "v"((unsigned long long)(uintptr_t)p), "i"(OFF));
    return r;
}
#define LGKM0()  asm volatile("s_waitcnt lgkmcnt(0)" ::: "memory")
#define VM0()    asm volatile("s_waitcnt vmcnt(0)" ::: "memory")
#define SCHED0() __builtin_amdgcn_sched_barrier(0)

// f32 -> bf16 round-to-nearest-even
__device__ __forceinline__ short f2bf(float x) {
    unsigned u = __float_as_uint(x);
    unsigned r = u + 0x7fffu + ((u >> 16) & 1u);
    return (short)(r >> 16);
}
__device__ __forceinline__ bf16x8 to8(f4v lo, f4v hi) {
    bf16x8 r;
    r[0]=f2bf(lo.x); r[1]=f2bf(lo.y); r[2]=f2bf(lo.z); r[3]=f2bf(lo.w);
    r[4]=f2bf(hi.x); r[5]=f2bf(hi.y); r[6]=f2bf(hi.z); r[7]=f2bf(hi.w);
    return r;
}

// ================= MFMA GEMM16 core: one wave, 16 cols, K-split of 512 =======
// A frag: x[lane&15][k-slice], B frag: W[col=cb+(lane&15)][same k-slice];
// identical (lane>>4,elem)->k map on both operands cancels any k-permutation.
// 4-chunk load ring in registers, counted vmcnt ladder, no LDS, no barriers.
__device__ __forceinline__ f4v gemm16_512(const float* a, const float* wp) {
    f4v acc = {0.f, 0.f, 0.f, 0.f};
    f4v al[4][2], bl[4][2];
#define ISSUE(c) \
    al[(c)&3][0] = gload_off<(c)*128>(a);      \
    al[(c)&3][1] = gload_off<(c)*128+16>(a);   \
    bl[(c)&3][0] = gload_off<(c)*128>(wp);     \
    bl[(c)&3][1] = gload_off<(c)*128+16>(wp);
#define STEP(c) { \
    if ((c) <= 12)      asm volatile("s_waitcnt vmcnt(12)" ::: "memory"); \
    else if ((c) == 13) asm volatile("s_waitcnt vmcnt(8)"  ::: "memory"); \
    else if ((c) == 14) asm volatile("s_waitcnt vmcnt(4)"  ::: "memory"); \
    else                asm volatile("s_waitcnt vmcnt(0)"  ::: "memory"); \
    SCHED0(); \
    { bf16x8 af = to8(al[(c)&3][0], al[(c)&3][1]); \
      bf16x8 bf = to8(bl[(c)&3][0], bl[(c)&3][1]); \
      acc = __builtin_amdgcn_mfma_f32_16x16x32_bf16(af, bf, acc, 0, 0, 0); } \
    if ((c) + 4 < 16) { ISSUE((c)+4) } }
    ISSUE(0) ISSUE(1) ISSUE(2) ISSUE(3)
    STEP(0)  STEP(1)  STEP(2)  STEP(3)
    STEP(4)  STEP(5)  STEP(6)  STEP(7)
    STEP(8)  STEP(9)  STEP(10) STEP(11)
    STEP(12) STEP(13) STEP(14) STEP(15)
#undef STEP
#undef ISSUE
    return acc;
}

// generic: C16xN partials, K-split S (512 each). grid = (N/64)*S blocks.
template<int K, int N, int S>
__global__ __launch_bounds__(256) void k_mm(const float* __restrict__ A,
                                            const float* __restrict__ W,
                                            float* __restrict__ part) {
    int tid = threadIdx.x, w = tid >> 6, lane = tid & 63;
    int nColBlk = N >> 6;
    int colblk = blockIdx.x % nColBlk, s = blockIdx.x / nColBlk;
    int cb = colblk * 64 + w * 16;
    int col = cb + (lane & 15), g = lane >> 4, k0 = s * 512;
    f4v acc = gemm16_512(A + (size_t)(lane & 15) * K + k0 + g * 8,
                         W + (size_t)col * K + k0 + g * 8);
    #pragma unroll
    for (int r = 0; r < 4; ++r)
        part[((size_t)(s * 16) + g * 4 + r) * N + col] = acc[r];
}

// fused QKV: 3 x (N=2048, S=4) -> 384 blocks
__global__ __launch_bounds__(256) void k_qkv_mm(const float* __restrict__ Xn,
                                                const float* __restrict__ Wq,
                                                const float* __restrict__ Wk,
                                                const float* __restrict__ Wv,
                                                float* __restrict__ pq,
                                                float* __restrict__ pk,
                                                float* __restrict__ pv) {
    int tid = threadIdx.x, w = tid >> 6, lane = tid & 63;
    int b = blockIdx.x;               // 0..383
    int sel = b >> 7, bb = b & 127;
    int colblk = bb & 31, s = bb >> 5;
    const float* W = (sel == 0) ? Wq : (sel == 1) ? Wk : Wv;
    float* part = (sel == 0) ? pq : (sel == 1) ? pk : pv;
    int cb = colblk * 64 + w * 16;
    int col = cb + (lane & 15), g = lane >> 4, k0 = s * 512;
    f4v acc = gemm16_512(Xn + (size_t)(lane & 15) * NDIM + k0 + g * 8,
                         W + (size_t)col * NDIM + k0 + g * 8);
    #pragma unroll
    for (int r = 0; r < 4; ++r)
        part[((size_t)(s * 16) + g * 4 + r) * NDIM + col] = acc[r];
}

// ================= epilogues =================
__device__ __forceinline__ float gelu_exact(float x) {
    return 0.5f * x * (1.0f + erff(x * 0.7071067811865475f));
}

__global__ __launch_bounds__(256) void ep_qkv(const float* __restrict__ pq,
                                              const float* __restrict__ pk,
                                              const float* __restrict__ pv,
                                              float* __restrict__ qws,
                                              float* __restrict__ kws,
                                              float* __restrict__ vws) {
    int i = blockIdx.x * 256 + threadIdx.x;          // 0..32767
    int m = i >> 11, gcol = i & 2047;
    float q = 0.f, k = 0.f, v = 0.f;
    #pragma unroll
    for (int s = 0; s < 4; ++s) {
        q += pq[(size_t)s * 32768 + i];
        k += pk[(size_t)s * 32768 + i];
        v += pv[(size_t)s * 32768 + i];
    }
    int h = gcol >> 7, d = gcol & 127;
    size_t o = (((size_t)h * 16 + m) << 7) + d;
    qws[o] = q; kws[o] = k; vws[o] = v;
}

__global__ __launch_bounds__(256) void ep_resid4(const float* __restrict__ p,
                                                 const float* __restrict__ R,
                                                 float* __restrict__ out) {
    int i = blockIdx.x * 256 + threadIdx.x;          // 32768
    float a = 0.f;
    #pragma unroll
    for (int s = 0; s < 4; ++s) a += p[(size_t)s * 32768 + i];
    out[i] = R[i] + a;
}

__global__ __launch_bounds__(256) void ep_up(const float* __restrict__ p,
                                             float* __restrict__ out) {
    int i = blockIdx.x * 256 + threadIdx.x;          // 131072
    float a = 0.f;
    #pragma unroll
    for (int s = 0; s < 4; ++s) a += p[(size_t)s * 131072 + i];
    out[i] = gelu_exact(a);
}

__global__ __launch_bounds__(256) void ep_resid16(const float* __restrict__ p,
                                                  const float* __restrict__ R,
                                                  float* __restrict__ out) {
    int i = blockIdx.x * 256 + threadIdx.x;          // 32768
    float a = 0.f;
    #pragma unroll
    for (int s = 0; s < 16; ++s) a += p[(size_t)s * 32768 + i];
    out[i] = R[i] + a;
}

// ---------------- LayerNorm ----------------
__global__ __launch_bounds__(256) void k_ln(const float* __restrict__ X,
                                            const float* __restrict__ g,
                                            const float* __restrict__ b,
                                            float* __restrict__ out) {
    int row = blockIdx.x, tid = threadIdx.x;
    const float4* xp = (const float4*)(X + (size_t)row * NDIM);
    float4 v0 = xp[tid], v1 = xp[tid + 256];
    float s = v0.x + v0.y + v0.z + v0.w + v1.x + v1.y + v1.z + v1.w;
    float q = v0.x*v0.x + v0.y*v0.y + v0.z*v0.z + v0.w*v0.w
            + v1.x*v1.x + v1.y*v1.y + v1.z*v1.z + v1.w*v1.w;
    #pragma unroll
    for (int o = 32; o; o >>= 1) { s += __shfl_xor(s, o); q += __shfl_xor(q, o); }
    __shared__ float ls[4], lq[4];
    int wid = tid >> 6, lane = tid & 63;
    if (lane == 0) { ls[wid] = s; lq[wid] = q; }
    __syncthreads();
    s = ls[0] + ls[1] + ls[2] + ls[3];
    q = lq[0] + lq[1] + lq[2] + lq[3];
    float mu  = s * (1.f / NDIM);
    float var = q * (1.f / NDIM) - mu * mu;
    float rs  = rsqrtf(var + LN_EPS);
    float4 g0 = ((const float4*)g)[tid], g1 = ((const float4*)g)[tid + 256];
    float4 b0 = ((const float4*)b)[tid], b1 = ((const float4*)b)[tid + 256];
    float4 o0, o1;
    o0.x = (v0.x - mu) * rs * g0.x + b0.x;  o0.y = (v0.y - mu) * rs * g0.y + b0.y;
    o0.z = (v0.z - mu) * rs * g0.z + b0.z;  o0.w = (v0.w - mu) * rs * g0.w + b0.w;
    o1.x = (v1.x - mu) * rs * g1.x + b1.x;  o1.y = (v1.y - mu) * rs * g1.y + b1.y;
    o1.z = (v1.z - mu) * rs * g1.z + b1.z;  o1.w = (v1.w - mu) * rs * g1.w + b1.w;
    float4* op = (float4*)(out + (size_t)row * NDIM);
    op[tid] = o0; op[tid + 256] = o1;
}

// ---------------- attention: MFMA bf16 (R12, unchanged) ----------------
__global__ __launch_bounds__(256) void k_attn(const float* __restrict__ cacheK,
                                              const float* __restrict__ cacheV,
                                              const float* __restrict__ qws,
                                              const float* __restrict__ kws,
                                              const float* __restrict__ vws,
                                              float* __restrict__ part,   // [16h][129c][16m][128d]
                                              float* __restrict__ ms) {   // [16h][129c][16m][2]
    __shared__ float s_k[TC * DHEAD];
    __shared__ float s_v[TC * DHEAD];
    __shared__ float s_p[16 * 68];
    int bid = blockIdx.x;
    int h = bid / NCH, c = bid % NCH;
    int nT = (c < NCH - 1) ? TC : M_TOK;
    bool full = (nT == TC);
    int nSeg = nT >> 1;
    const float* Kb = (c < NCH - 1) ? cacheK + ((size_t)h * MAXLEN + (size_t)c * TC) * DHEAD
                                    : kws + (size_t)h * M_TOK * DHEAD;
    const float* Vb = (c < NCH - 1) ? cacheV + ((size_t)h * MAXLEN + (size_t)c * TC) * DHEAD
                                    : vws + (size_t)h * M_TOK * DHEAD;
    int tid = threadIdx.x, w = tid >> 6, lane = tid & 63;
    int g = lane >> 4;

    #pragma unroll
    for (int k = 0; k < 8; ++k) {
        int j = w + 4 * k;
        if (j < nSeg) {
            int b = j * 1024 + lane * 16;
            int src = b ^ (((b >> 9) & 7) << 4);
            gload_lds16(Kb + (src >> 2), s_k + j * 256);
        }
    }

    int m_l = lane & 15;
    const float* qbase = qws + (size_t)h * M_TOK * DHEAD + (size_t)m_l * DHEAD;
    f4v qlo[4], qhi[4];
    #pragma unroll
    for (int blk = 0; blk < 4; ++blk) {
        qlo[blk] = gload_b128(qbase + blk * 32 + g * 4);
        qhi[blk] = gload_b128(qbase + blk * 32 + g * 4 + 16);
    }
    VM0();
    SCHED0();

    bf16x8 qf[4];
    #pragma unroll
    for (int blk = 0; blk < 4; ++blk) qf[blk] = to8(qlo[blk], qhi[blk]);

    #pragma unroll
    for (int k = 0; k < 8; ++k) {
        int j = w + 4 * k;
        if (j < nSeg) {
            int b = j * 1024 + lane * 16;
            int src = b ^ (((b >> 9) & 7) << 4);
            gload_lds16(Vb + (src >> 2), s_v + j * 256);
        }
    }
    __builtin_amdgcn_s_barrier();

    const uint32_t skb = lds_off(s_k);
    const uint32_t svb = lds_off(s_v);
    const uint32_t spb = lds_off(s_p);

    int t0 = w * 16;
    if (t0 < nT) {
        int trow = t0 + (lane & 15);
        uint32_t xo = (uint32_t)((trow & 7) << 4);
        f4v klo[4], khi[4];
        #pragma unroll
        for (int blk = 0; blk < 4; ++blk) {
            uint32_t base = (uint32_t)(trow * 512 + blk * 128 + g * 16);
            klo[blk] = dsr_b128(skb + ((base)      ^ xo));
            khi[blk] = dsr_b128(skb + ((base + 64) ^ xo));
        }
        LGKM0();
        SCHED0();
        f4v accS = {0.f, 0.f, 0.f, 0.f};
        #pragma unroll
        for (int blk = 0; blk < 4; ++blk) {
            bf16x8 bk = to8(klo[blk], khi[blk]);
            accS = __builtin_amdgcn_mfma_f32_16x16x32_bf16(qf[blk], bk, accS, 0, 0, 0);
        }
        #pragma unroll
        for (int r = 0; r < 4; ++r) {
            int m = g * 4 + r;
            dsw_b32(spb + (uint32_t)((m * 68 + t0 + (lane & 15)) * 4), accS[r] * RSQRT_D);
        }
    }
    LGKM0();
    __builtin_amdgcn_s_barrier();

    int m2 = tid >> 4, tl = tid & 15;
    float sm_mx, sm_sum;
    {
        uint32_t prow = spb + (uint32_t)(m2 * 68 * 4);
        float r0 = dsr_b32(prow + (uint32_t)(tl * 4));
        float r1 = -1e30f, r2 = -1e30f, r3 = -1e30f;
        if (full) {
            r1 = dsr_b32(prow + (uint32_t)((tl + 16) * 4));
            r2 = dsr_b32(prow + (uint32_t)((tl + 32) * 4));
            r3 = dsr_b32(prow + (uint32_t)((tl + 48) * 4));
        }
        LGKM0();
        SCHED0();
        float mx = fmaxf(fmaxf(r0, r1), fmaxf(r2, r3));
        #pragma unroll
        for (int o = 8; o; o >>= 1) mx = fmaxf(mx, __shfl_xor(mx, o));
        float p0 = __expf(r0 - mx), sum = p0;
        dsw_b32(prow + (uint32_t)(tl * 4), p0);
        if (full) {
            float p1 = __expf(r1 - mx), p2 = __expf(r2 - mx), p3 = __expf(r3 - mx);
            sum += p1 + p2 + p3;
            dsw_b32(prow + (uint32_t)((tl + 16) * 4), p1);
            dsw_b32(prow + (uint32_t)((tl + 32) * 4), p2);
            dsw_b32(prow + (uint32_t)((tl + 48) * 4), p3);
        }
        #pragma unroll
        for (int o = 8; o; o >>= 1) sum += __shfl_xor(sum, o);
        sm_mx = mx; sm_sum = sum;
    }
    LGKM0();
    VM0();
    __builtin_amdgcn_s_barrier();

    if (!full) {
        for (int i = tid; i < 16 * 128; i += 256) {
            int r = 16 + (i >> 7), dd = i & 127;
            dsw_b32(svb + (uint32_t)((r * 512 + dd * 4) ^ ((r & 7) << 4)), 0.f);
        }
        { int m = tid >> 4, t = 16 + (tid & 15);
          dsw_b32(spb + (uint32_t)((m * 68 + t) * 4), 0.f); }
        LGKM0();
        __builtin_amdgcn_s_barrier();
    }

    f4v accO0 = {0.f,0.f,0.f,0.f}, accO1 = {0.f,0.f,0.f,0.f};
    int dc0 = w * 32 + (lane & 15);
    int nTC = (nT + 31) >> 5;
    #pragma unroll
    for (int tc = 0; tc < 2; ++tc) {
        if (tc >= nTC) break;
        int m = lane & 15;
        f4v plo = dsr_b128(spb + (uint32_t)((m * 68 + tc * 32 + g * 4) * 4));
        f4v phi = dsr_b128(spb + (uint32_t)((m * 68 + tc * 32 + g * 4 + 16) * 4));
        float va[8], vb_[8];
        #pragma unroll
        for (int half = 0; half < 2; ++half) {
            #pragma unroll
            for (int jj = 0; jj < 4; ++jj) {
                int t = tc * 32 + g * 4 + jj + half * 16;
                uint32_t xo = (uint32_t)((t & 7) << 4);
                va[half*4+jj]  = dsr_b32(svb + ((uint32_t)(t * 512 + dc0 * 4)      ^ xo));
                vb_[half*4+jj] = dsr_b32(svb + ((uint32_t)(t * 512 + (dc0+16) * 4) ^ xo));
            }
        }
        LGKM0();
        SCHED0();
        bf16x8 pa;
        pa[0] = f2bf(plo.x); pa[1] = f2bf(plo.y); pa[2] = f2bf(plo.z); pa[3] = f2bf(plo.w);
        pa[4] = f2bf(phi.x); pa[5] = f2bf(phi.y); pa[6] = f2bf(phi.z); pa[7] = f2bf(phi.w);
        bf16x8 v0, v1;
        #pragma unroll
        for (int j = 0; j < 8; ++j) { v0[j] = f2bf(va[j]); v1[j] = f2bf(vb_[j]); }
        accO0 = __builtin_amdgcn_mfma_f32_16x16x32_bf16(pa, v0, accO0, 0, 0, 0);
        accO1 = __builtin_amdgcn_mfma_f32_16x16x32_bf16(pa, v1, accO1, 0, 0, 0);
    }

    float* pb = part + ((size_t)(h * NCH + c) * 16) * DHEAD;
    #pragma unroll
    for (int r = 0; r < 4; ++r) {
        int m = g * 4 + r;
        pb[(size_t)m * DHEAD + dc0]      = accO0[r];
        pb[(size_t)m * DHEAD + dc0 + 16] = accO1[r];
    }
    if (tl == 0) {
        float* msp = ms + ((size_t)(h * NCH + c) * 16 + m2) * 2;
        msp[0] = sm_mx; msp[1] = sm_sum;
    }
}

// ---------------- combine chunk partials ----------------
__global__ __launch_bounds__(256) void k_combine(const float* __restrict__ part,
                                                 const float* __restrict__ ms,
                                                 float* __restrict__ attnout) {
    __shared__ float s_scale[16][NCH + 3];
    int h = blockIdx.x >> 3, dblk = blockIdx.x & 7;
    int tid = threadIdx.x;
    {
        int cl = tid & 15, m = tid >> 4;
        float gmax = -1e30f;
        for (int c = cl; c < NCH; c += 16)
            gmax = fmaxf(gmax, ms[((size_t)(h * NCH + c) * 16 + m) * 2]);
        #pragma unroll
        for (int o = 8; o; o >>= 1) gmax = fmaxf(gmax, __shfl_xor(gmax, o));
        float denom = 0.f;
        for (int c = cl; c < NCH; c += 16) {
            const float* msp = ms + ((size_t)(h * NCH + c) * 16 + m) * 2;
            denom += msp[1] * __expf(msp[0] - gmax);
        }
        #pragma unroll
        for (int o = 8; o; o >>= 1) denom += __shfl_xor(denom, o);
        float inv = 1.f / denom;
        for (int c = cl; c < NCH; c += 16) {
            const float* msp = ms + ((size_t)(h * NCH + c) * 16 + m) * 2;
            s_scale[m][c] = __expf(msp[0] - gmax) * inv;
        }
    }
    __syncthreads();
    int m = tid >> 4, dd = tid & 15;
    int d = dblk * 16 + dd;
    const float* pp = part + ((size_t)h * NCH * 16 + m) * DHEAD + d;
    float acc = 0.f;
    #pragma unroll 4
    for (int c = 0; c < NCH; ++c)
        acc = fmaf(pp[(size_t)c * 16 * DHEAD], s_scale[m][c], acc);
    attnout[(size_t)m * NDIM + h * DHEAD + d] = acc;
}

// ---------------- launcher ----------------
extern "C" void kernel_launch(void* const* d_in, const int* in_sizes, int n_in,
                              void* d_out, int out_size, void* d_ws, size_t ws_size,
                              hipStream_t stream) {
    const float* X      = (const float*)d_in[0];
    const float* ln1_g  = (const float*)d_in[1];
    const float* ln1_b  = (const float*)d_in[2];
    const float* Wq     = (const float*)d_in[3];
    const float* Wk     = (const float*)d_in[4];
    const float* Wv     = (const float*)d_in[5];
    const float* Wo     = (const float*)d_in[6];
    const float* ln2_g  = (const float*)d_in[7];
    const float* ln2_b  = (const float*)d_in[8];
    const float* Wup    = (const float*)d_in[9];
    const float* Wdown  = (const float*)d_in[10];
    const float* cacheK = (const float*)d_in[11];
    const float* cacheV = (const float*)d_in[12];
    float* out = (float*)d_out;

    float* ws = (float*)d_ws;
    float* Xn1    = ws;                       // 32768
    float* qws    = Xn1 + 32768;              // 32768
    float* kws    = qws + 32768;              // 32768
    float* vws    = kws + 32768;              // 32768
    float* partb  = vws + 32768;              // 16*129*16*128 = 4227072
    float* msb    = partb + 4227072;          // 66048
    float* attn_o = msb + 66048;              // 32768
    float* X2     = attn_o + 32768;           // 32768
    float* Xn2    = X2 + 32768;               // 32768
    float* ffnh   = Xn2 + 32768;              // 131072
    float* pq     = ffnh + 131072;            // 4*32768 = 131072
    float* pk     = pq + 131072;              // 131072
    float* pv     = pk + 131072;              // 131072
    float* po     = pv + 131072;              // 131072
    float* pu     = po + 131072;              // 4*131072 = 524288
    float* pd     = pu + 524288;              // 16*32768 = 524288

    k_ln<<<M_TOK, 256, 0, stream>>>(X, ln1_g, ln1_b, Xn1);
    k_qkv_mm<<<384, 256, 0, stream>>>(Xn1, Wq, Wk, Wv, pq, pk, pv);
    ep_qkv<<<128, 256, 0, stream>>>(pq, pk, pv, qws, kws, vws);
    k_attn<<<NHEAD * NCH, 256, 0, stream>>>(cacheK, cacheV, qws, kws, vws, partb, msb);
    k_combine<<<NHEAD * 8, 256, 0, stream>>>(partb, msb, attn_o);
    k_mm<2048, 2048, 4><<<128, 256, 0, stream>>>(attn_o, Wo, po);
    ep_resid4<<<128, 256, 0, stream>>>(po, X, X2);
    k_ln<<<M_TOK, 256, 0, stream>>>(X2, ln2_g, ln2_b, Xn2);
    k_mm<2048, 8192, 4><<<512, 256, 0, stream>>>(Xn2, Wup, pu);
    ep_up<<<512, 256, 0, stream>>>(pu, ffnh);
    k_mm<8192, 2048, 16><<<512, 256, 0, stream>>>(ffnh, Wdown, pd);
    ep_resid16<<<128, 256, 0, stream>>>(pd, X2, out);
}